// Round 8
// baseline (138.127 us; speedup 1.0000x reference)
//
#include <hip/hip_runtime.h>
#include <hip/hip_bf16.h>

// B=1, H=8, L=4096, D=64; 64x64 blocks; 16 samples/block. Inputs f32, output f32.
#define H_ 8
#define L_ 4096
#define D_ 64
#define NB_ 64

typedef __attribute__((ext_vector_type(8))) short bf16x8;
typedef __attribute__((ext_vector_type(4))) float f32x4;

__device__ __forceinline__ unsigned short f2bf(float x) {   // RNE f32->bf16
    unsigned u = __float_as_uint(x);
    u += 0x7fff + ((u >> 16) & 1);
    return (unsigned short)(u >> 16);
}
__device__ __forceinline__ float bf2f(unsigned short s) {
    return __uint_as_float(((unsigned)s) << 16);
}

// ---------------------------------------------------------------------------
// Preprocess (unchanged — qlo still produced for mask_mfma).
// ---------------------------------------------------------------------------
__global__ __launch_bounds__(256) void prep_kernel(
    const float* __restrict__ q, const float* __restrict__ k, const float* __restrict__ v,
    const int* __restrict__ sidxk,
    unsigned short* __restrict__ qhi, unsigned short* __restrict__ qlo,
    unsigned short* __restrict__ khi,
    unsigned short* __restrict__ vth,
    unsigned short* __restrict__ skh, unsigned short* __restrict__ skl)
{
    const int h  = blockIdx.x >> 6;
    const int tb = blockIdx.x & 63;
    const int tid = threadIdx.x;
    __shared__ float vst[64][68];

    const size_t te = ((size_t)(h*64 + tb)) << 12;   // tile base (elements)
    const float4* qg = (const float4*)(q + te);
    for (int i4 = tid; i4 < 1024; i4 += 256) {
        float4 t = qg[i4];
        ushort4 hi, lo;
        hi.x = f2bf(t.x); lo.x = f2bf(t.x - bf2f(hi.x));
        hi.y = f2bf(t.y); lo.y = f2bf(t.y - bf2f(hi.y));
        hi.z = f2bf(t.z); lo.z = f2bf(t.z - bf2f(hi.z));
        hi.w = f2bf(t.w); lo.w = f2bf(t.w - bf2f(hi.w));
        *(ushort4*)(qhi + te + i4*4) = hi;
        *(ushort4*)(qlo + te + i4*4) = lo;
    }
    const float4* kg = (const float4*)(k + te);
    for (int i4 = tid; i4 < 1024; i4 += 256) {
        float4 t = kg[i4];
        int r = i4 >> 4, c4 = i4 & 15;
        int sch = (c4 >> 1) ^ ((r >> 2) & 7);   // matches attn's permuted-key S tiles
        ushort4 hi;
        hi.x = f2bf(t.x); hi.y = f2bf(t.y); hi.z = f2bf(t.z); hi.w = f2bf(t.w);
        *(ushort4*)(khi + te + r*64 + sch*8 + (c4 & 1)*4) = hi;
    }
    // sampled-K rows for the MFMA mask
    {
        int t = tid >> 4, d4 = tid & 15;
        int srow = tb*64 + sidxk[h*16 + t];
        float4 x = *(const float4*)(k + ((size_t)h*L_ + srow)*D_ + d4*4);
        ushort4 hi, lo;
        hi.x = f2bf(x.x); lo.x = f2bf(x.x - bf2f(hi.x));
        hi.y = f2bf(x.y); lo.y = f2bf(x.y - bf2f(hi.y));
        hi.z = f2bf(x.z); lo.z = f2bf(x.z - bf2f(hi.z));
        hi.w = f2bf(x.w); lo.w = f2bf(x.w - bf2f(hi.w));
        int sch = (d4 >> 1) ^ (t & 7);
        size_t dst = ((size_t)h*1024 + tb*16 + t)*64 + sch*8 + (d4 & 1)*4;
        *(ushort4*)(skh + dst) = hi;
        *(ushort4*)(skl + dst) = lo;
    }
    const float4* vg = (const float4*)(v + te);
    for (int i4 = tid; i4 < 1024; i4 += 256) {
        float4 t = vg[i4];
        *(float4*)&vst[i4 >> 4][(i4 & 15)*4] = t;
    }
    __syncthreads();
    for (int u = tid; u < 512; u += 256) {
        int d = u >> 3, kc8 = u & 7;
        int sch = kc8 ^ (d & 7);
        ushort4 h0, h1;
        h0.x = f2bf(vst[kc8*8+0][d]); h0.y = f2bf(vst[kc8*8+1][d]);
        h0.z = f2bf(vst[kc8*8+2][d]); h0.w = f2bf(vst[kc8*8+3][d]);
        h1.x = f2bf(vst[kc8*8+4][d]); h1.y = f2bf(vst[kc8*8+5][d]);
        h1.z = f2bf(vst[kc8*8+6][d]); h1.w = f2bf(vst[kc8*8+7][d]);
        *(ushort4*)(vth + te + d*64 + sch*8 + 0) = h0;
        *(ushort4*)(vth + te + d*64 + sch*8 + 4) = h1;
    }
}

// ---------------------------------------------------------------------------
// Kernel A (v5.2): MFMA block mask. Unchanged.
// ---------------------------------------------------------------------------
__global__ __launch_bounds__(256, 4) void mask_mfma(
    const unsigned short* __restrict__ qhi, const unsigned short* __restrict__ qlo,
    const unsigned short* __restrict__ skh, const unsigned short* __restrict__ skl,
    const int* __restrict__ sidxq,
    unsigned long long* __restrict__ maskbits)
{
    const int h    = blockIdx.x & 7;    // XCD-affinity remap
    const int qb   = blockIdx.x >> 3;
    const int tid  = threadIdx.x;
    const int wave = tid >> 6;
    const int lane = tid & 63;
    const int l16  = lane & 15;
    const int quad = lane >> 4;

    __shared__ __align__(16) unsigned short ch[8192];
    __shared__ __align__(16) unsigned short cl[8192];
    __shared__ float E[16][64];
    __shared__ float Z[16];
    __shared__ float pooled[64];

    for (int e = tid; e < 16*64; e += 256) (&E[0][0])[e] = 0.f;

    const int iqr = sidxq[h*16 + l16];
    const size_t qo = (((size_t)(h*64 + qb)) << 12) + (size_t)iqr*64;
    bf16x8 qh[2], ql[2];
    qh[0] = *(const bf16x8*)(qhi + qo + quad*8);
    qh[1] = *(const bf16x8*)(qhi + qo + 32 + quad*8);
    ql[0] = *(const bf16x8*)(qlo + qo + quad*8);
    ql[1] = *(const bf16x8*)(qlo + qo + 32 + quad*8);
    __syncthreads();

    for (int cc = 0; cc < 8; ++cc) {
        const bf16x8* gh = (const bf16x8*)(skh + ((size_t)h*1024 + cc*128)*64);
        const bf16x8* gl = (const bf16x8*)(skl + ((size_t)h*1024 + cc*128)*64);
        for (int i = tid; i < 1024; i += 256) {
            ((bf16x8*)ch)[i] = gh[i];
            ((bf16x8*)cl)[i] = gl[i];
        }
        __syncthreads();

        #pragma unroll
        for (int tt = 0; tt < 2; ++tt) {
            const int kb = cc*8 + wave*2 + tt;
            const int nb = (wave*2 + tt)*16;
            f32x4 sacc = (f32x4){0.f, 0.f, 0.f, 0.f};
            #pragma unroll
            for (int kc = 0; kc < 2; ++kc) {
                const int off = (nb + l16)*64 + (((kc*4 + quad) ^ (l16 & 7))*8);
                bf16x8 kh = *(const bf16x8*)&ch[off];
                bf16x8 kl = *(const bf16x8*)&cl[off];
                sacc = __builtin_amdgcn_mfma_f32_16x16x32_bf16(qh[kc], kh, sacc, 0, 0, 0);
                sacc = __builtin_amdgcn_mfma_f32_16x16x32_bf16(qh[kc], kl, sacc, 0, 0, 0);
                sacc = __builtin_amdgcn_mfma_f32_16x16x32_bf16(ql[kc], kh, sacc, 0, 0, 0);
                sacc = __builtin_amdgcn_mfma_f32_16x16x32_bf16(ql[kc], kl, sacc, 0, 0, 0);
            }
            #pragma unroll
            for (int r = 0; r < 4; ++r) {
                float p = __expf(sacc[r] * 0.125f);
                p += __shfl_xor(p, 1);
                p += __shfl_xor(p, 2);
                p += __shfl_xor(p, 4);
                p += __shfl_xor(p, 8);
                if (l16 == 0) E[quad*4 + r][kb] = p;
            }
        }
        __syncthreads();
    }

    if (tid < 16) {
        float s = 0.f;
        #pragma unroll
        for (int kb = 0; kb < 64; ++kb) s += E[tid][kb];
        Z[tid] = s;
    }
    __syncthreads();
    if (tid < 64) {
        float s = 0.f;
        #pragma unroll
        for (int t = 0; t < 16; ++t) s += E[t][tid] / Z[t];
        pooled[tid] = s;
    }
    __syncthreads();
    if (tid < 64) {
        float pi = pooled[tid];
        float tot = 0.f, bef = 0.f;
        for (int j2 = 0; j2 < 64; ++j2) {
            float pj = pooled[j2];
            tot += pj;
            if (pj > pi || (pj == pi && j2 < tid)) bef += pj;
        }
        bool att = (bef / tot) < 0.5f;
        unsigned long long bits = __ballot(att);
        if (tid == 0) maskbits[h*64 + qb] = bits;
    }
}

// ---------------------------------------------------------------------------
// Kernel B (v14): Q-SPLIT 8-wave wave-independent attention, 4 waves/SIMD.
// ROUND 18. Budget audit: per-SIMD issue sum ~= 8-10us but measured ~31us ->
// packing ~30%; R0 counters showed Occupancy 17% (1.4 waves/SIMD), now VGPR
// ~200 caps at 2 waves/SIMD. R12's "occupancy null" was the barrier-gang
// structure (waves stall in phase) - does not transfer to wave-independent.
// This round targets <=128 VGPR -> 4 waves/SIMD:
//  - 512-thr blocks, 8 waves: waves 0-3 = q-rows 0-31, waves 4-7 = 32-63
//    (oacc 64->32, lacc 16->8). Within a half, waves stride k-blocks 4-way.
//    K/V L2 traffic x2 (2 waves/tile) = 1.4 TB/s/XCD, 3x under L2 BW.
//  - K and V TIME-SHARE one 32-reg block: K lives during QK; V loaded after
//    last K use (covered by softmax VALU); next-K issued at loop tail.
//  - __launch_bounds__(512,4) pins VGPR cap 128. LDS 66.5KB -> 2 blocks/CU
//    = 16 waves/CU = 4/SIMD.
// Per-tile math bit-identical to v13; reduce keeps 4 partials/row.
// ---------------------------------------------------------------------------
__global__ __launch_bounds__(512, 4) void attn_qsplit(
    const unsigned short* __restrict__ qhi,
    const unsigned short* __restrict__ khi,
    const unsigned short* __restrict__ vth,
    const unsigned long long* __restrict__ maskbits,
    float* __restrict__ out)
{
    const int h    = blockIdx.x & 7;    // XCD-affinity remap
    const int qb   = blockIdx.x >> 3;
    const int tid  = threadIdx.x;
    const int wave = tid >> 6;
    const int lane = tid & 63;
    const int l16  = lane & 15;
    const int quad = lane >> 4;
    const int qhalf = wave >> 2;        // q-rows qhalf*32 .. +31
    const int kw    = wave & 3;         // k-stride rank within the half

    // LDS union: stream = Qh[64][72] (9216B) + ps[8 waves][32][88] (45056B)
    //            reduce = ored[4][64][64] f32 (65536B) + lred[4][64] (1024B)
    __shared__ __align__(16) char SM[66560];
    unsigned short* Qh = (unsigned short*)SM;                         // [64][72]
    unsigned short* ps = (unsigned short*)(SM + 9216 + wave*5632);    // [32][88]

    const size_t qbase = ((size_t)(h*64 + qb)) << 12;

    // ---- stage swizzled Q (hi) to LDS: 512 threads, one uint4 each ----
    {
        int row = tid >> 3, cc = tid & 7;
        int sw = cc ^ ((row >> 2) & 7);
        *(uint4*)&Qh[row*72 + sw*8] = *(const uint4*)(qhi + qbase + row*64 + cc*8);
    }

    // ---- my k-block list: every 4th set bit, starting at rank kw ----
    unsigned long long rem = maskbits[(h << 6) + qb];
    for (int s = 0; s < kw; ++s) rem &= rem - 1;
    int cur = rem ? (int)__builtin_ctzll(rem) : -1;

    const bf16x8 ones = {0x3F80, 0x3F80, 0x3F80, 0x3F80, 0x3F80, 0x3F80, 0x3F80, 0x3F80};

    f32x4 lacc[2];
    f32x4 oacc[2][4];
    #pragma unroll
    for (int qt = 0; qt < 2; ++qt) {
        lacc[qt] = (f32x4){0.f, 0.f, 0.f, 0.f};
        #pragma unroll
        for (int dt = 0; dt < 4; ++dt) oacc[qt][dt] = (f32x4){0.f, 0.f, 0.f, 0.f};
    }

    // lane byte-offsets: K frag = koff + t*128 (^64 for kc=1); V = voff + dt*2048
    const unsigned swz  = (unsigned)((quad ^ (l16 & 7)) * 16);
    const unsigned koff = (unsigned)l16*512 + swz;
    const unsigned voff = (unsigned)l16*128 + swz;

    bf16x8 kv[4][2];                    // time-shared: K during QK, V during PV
    if (cur >= 0) {
        const char* kb = (const char*)khi + (((size_t)(h*64 + cur)) << 13);
        #pragma unroll
        for (int t = 0; t < 4; ++t) {
            kv[t][0] = *(const bf16x8*)(kb + (koff + t*128));
            kv[t][1] = *(const bf16x8*)(kb + ((koff ^ 64) + t*128));
        }
    }
    __syncthreads();   // Q published

    auto qk = [&](int gqt, f32x4* sacc) {
        const int xb = (gqt*4 + (l16 >> 2)) & 7;
        bf16x8 ah[2];
        #pragma unroll
        for (int kc = 0; kc < 2; ++kc)
            ah[kc] = *(const bf16x8*)&Qh[(gqt*16 + l16)*72 + (((kc*4 + quad) ^ xb)*8)];
        #pragma unroll
        for (int t = 0; t < 4; ++t) {
            f32x4 s = (f32x4){0.f, 0.f, 0.f, 0.f};
            s = __builtin_amdgcn_mfma_f32_16x16x32_bf16(ah[0], kv[t][0], s, 0, 0, 0);
            s = __builtin_amdgcn_mfma_f32_16x16x32_bf16(ah[1], kv[t][1], s, 0, 0, 0);
            sacc[t] = s;
        }
    };
    auto sm = [&](int qt, f32x4* sacc) {
        #pragma unroll
        for (int r = 0; r < 4; ++r) {
            float p0 = __builtin_amdgcn_exp2f(fmaf(sacc[0][r], 0.18033688f, -23.083121f));
            float p1 = __builtin_amdgcn_exp2f(fmaf(sacc[1][r], 0.18033688f, -23.083121f));
            float p2 = __builtin_amdgcn_exp2f(fmaf(sacc[2][r], 0.18033688f, -23.083121f));
            float p3 = __builtin_amdgcn_exp2f(fmaf(sacc[3][r], 0.18033688f, -23.083121f));
            __hip_bfloat162 a01 = __float22bfloat162_rn(make_float2(p0, p1));
            __hip_bfloat162 a23 = __float22bfloat162_rn(make_float2(p2, p3));
            uint2 w; w.x = *(unsigned*)&a01; w.y = *(unsigned*)&a23;
            *(uint2*)&ps[(qt*16 + quad*4 + r)*88 + l16*4] = w;
        }
    };

    while (cur >= 0) {
        rem &= rem - 1; rem &= rem - 1; rem &= rem - 1; rem &= rem - 1;  // pop 4
        const int nxt = rem ? (int)__builtin_ctzll(rem) : -1;
        const char* vb = (const char*)vth + (((size_t)(h*64 + cur)) << 13);

        {   // QK + SM, q-tile 0 of my half
            f32x4 s0[4];
            qk(qhalf*2 + 0, s0);
            sm(0, s0);
        }
        {   // QK q-tile 1; then V loads reuse the kv regs; SM1 covers V latency
            f32x4 s1[4];
            qk(qhalf*2 + 1, s1);
            #pragma unroll
            for (int dt = 0; dt < 4; ++dt) {
                kv[dt][0] = *(const bf16x8*)(vb + (voff + dt*2048));
                kv[dt][1] = *(const bf16x8*)(vb + ((voff ^ 64) + dt*2048));
            }
            sm(1, s1);
        }
        // ---- PV + l-rowsum (ps wave-local; compiler inserts lgkmcnt) ----
        #pragma unroll
        for (int qt = 0; qt < 2; ++qt) {
            bf16x8 pf0 = *(const bf16x8*)&ps[(qt*16 + l16)*88 + quad*8];
            bf16x8 pf1 = *(const bf16x8*)&ps[(qt*16 + l16)*88 + 32 + quad*8];
            lacc[qt] = __builtin_amdgcn_mfma_f32_16x16x32_bf16(pf0, ones, lacc[qt], 0, 0, 0);
            lacc[qt] = __builtin_amdgcn_mfma_f32_16x16x32_bf16(pf1, ones, lacc[qt], 0, 0, 0);
            #pragma unroll
            for (int dt = 0; dt < 4; ++dt) {
                oacc[qt][dt] = __builtin_amdgcn_mfma_f32_16x16x32_bf16(pf0, kv[dt][0], oacc[qt][dt], 0, 0, 0);
                oacc[qt][dt] = __builtin_amdgcn_mfma_f32_16x16x32_bf16(pf1, kv[dt][1], oacc[qt][dt], 0, 0, 0);
            }
        }
        // ---- tail: next-K into kv (covered by loop-top Q reads + TLP) ----
        if (nxt >= 0) {
            const char* kb = (const char*)khi + (((size_t)(h*64 + nxt)) << 13);
            #pragma unroll
            for (int t = 0; t < 4; ++t) {
                kv[t][0] = *(const bf16x8*)(kb + (koff + t*128));
                kv[t][1] = *(const bf16x8*)(kb + ((koff ^ 64) + t*128));
            }
        }
        cur = nxt;
    }

    // ---- cross-wave reduce: O = sum_kw O / sum_kw l ----
    __syncthreads();   // stream LDS dead
    float* ored = (float*)SM;            // [4][64][64]
    float* lred = (float*)(SM + 65536);  // [4][64]
    #pragma unroll
    for (int qt = 0; qt < 2; ++qt) {
        const int gr0 = qhalf*32 + qt*16 + quad*4;
        #pragma unroll
        for (int dt = 0; dt < 4; ++dt)
            #pragma unroll
            for (int r = 0; r < 4; ++r)
                ored[(kw*64 + gr0 + r)*64 + dt*16 + l16] = oacc[qt][dt][r];
        if (l16 == 0) {
            #pragma unroll
            for (int r = 0; r < 4; ++r)
                lred[kw*64 + gr0 + r] = lacc[qt][r];
        }
    }
    __syncthreads();
    {
        const int row = tid >> 3;
        const int d0  = (tid & 7) << 3;
        float l = lred[row] + lred[64 + row] + lred[128 + row] + lred[192 + row];
        float inv = 1.f / l;
        float* og = out + ((size_t)h*L_ + (size_t)qb*64 + row)*D_ + d0;
        #pragma unroll
        for (int j = 0; j < 8; j += 4) {
            float4 a = *(float4*)&ored[0*4096 + row*64 + d0 + j];
            float4 b = *(float4*)&ored[1*4096 + row*64 + d0 + j];
            float4 c = *(float4*)&ored[2*4096 + row*64 + d0 + j];
            float4 d = *(float4*)&ored[3*4096 + row*64 + d0 + j];
            float4 rr;
            rr.x = (a.x + b.x + c.x + d.x) * inv;
            rr.y = (a.y + b.y + c.y + d.y) * inv;
            rr.z = (a.z + b.z + c.z + d.z) * inv;
            rr.w = (a.w + b.w + c.w + d.w) * inv;
            *(float4*)(og + j) = rr;
        }
    }
}

// ---------------------------------------------------------------------------
// Fallback path (round-6, proven): mask_kernel4 + attn_v3, only if ws small.
// ---------------------------------------------------------------------------
__global__ __launch_bounds__(256, 4) void mask_kernel4(
    const float* __restrict__ q, const float* __restrict__ k,
    const int* __restrict__ sidxq, const int* __restrict__ sidxk,
    unsigned long long* __restrict__ maskbits)
{
    const int h   = blockIdx.x >> 6;
    const int qb  = blockIdx.x & 63;
    const int tid = threadIdx.x;
    const int rg  = tid >> 5;
    const int cg  = tid & 31;

    __shared__ float sq[16][68];
    __shared__ float skc[128][68];
    __shared__ float E[16][64];
    __shared__ float Z[16];
    __shared__ float pooled[64];
    __shared__ int iq[16], ik[16];

    if (tid < 16) { iq[tid] = sidxq[h*16 + tid]; ik[tid] = sidxk[h*16 + tid]; }
    for (int e = tid; e < 16*64; e += 256) (&E[0][0])[e] = 0.f;
    __syncthreads();
    {
        int j = tid >> 4, d4 = tid & 15;
        int grow = h*L_ + qb*64 + iq[j];
        *(float4*)&sq[j][d4*4] = *(const float4*)(q + (size_t)grow*D_ + d4*4);
    }
    for (int cc = 0; cc < 8; ++cc) {
        for (int i = tid; i < 2048; i += 256) {
            int col = i >> 4, d4 = i & 15;
            int colg = cc*128 + col;
            int grow = h*L_ + (colg >> 4)*64 + ik[colg & 15];
            *(float4*)&skc[col][d4*4] = *(const float4*)(k + (size_t)grow*D_ + d4*4);
        }
        __syncthreads();
        float acc[2][4] = {{0.f,0.f,0.f,0.f},{0.f,0.f,0.f,0.f}};
        #pragma unroll 4
        for (int d4 = 0; d4 < 16; ++d4) {
            float4 qv0 = *(const float4*)&sq[rg*2 + 0][d4*4];
            float4 qv1 = *(const float4*)&sq[rg*2 + 1][d4*4];
            #pragma unroll
            for (int j = 0; j < 4; ++j) {
                float4 kv = *(const float4*)&skc[cg + 32*j][d4*4];
                acc[0][j] += qv0.x*kv.x + qv0.y*kv.y + qv0.z*kv.z + qv0.w*kv.w;
                acc[1][j] += qv1.x*kv.x + qv1.y*kv.y + qv1.z*kv.z + qv1.w*kv.w;
            }
        }
        #pragma unroll
        for (int j = 0; j < 4; ++j) {
            int kb = cc*8 + (cg >> 4) + 2*j;
            #pragma unroll
            for (int i = 0; i < 2; ++i) {
                float p = __expf(acc[i][j] * 0.125f);
                p += __shfl_xor(p, 1);
                p += __shfl_xor(p, 2);
                p += __shfl_xor(p, 4);
                p += __shfl_xor(p, 8);
                if ((cg & 15) == 0) E[rg*2 + i][kb] += p;
            }
        }
        __syncthreads();
    }
    if (tid < 16) {
        float s = 0.f;
        #pragma unroll
        for (int kb = 0; kb < 64; ++kb) s += E[tid][kb];
        Z[tid] = s;
    }
    __syncthreads();
    if (tid < 64) {
        float s = 0.f;
        #pragma unroll
        for (int t = 0; t < 16; ++t) s += E[t][tid] / Z[t];
        pooled[tid] = s;
    }
    __syncthreads();
    if (tid < 64) {
        float pi = pooled[tid];
        float tot = 0.f, bef = 0.f;
        for (int j2 = 0; j2 < 64; ++j2) {
            float pj = pooled[j2];
            tot += pj;
            if (pj > pi || (pj == pi && j2 < tid)) bef += pj;
        }
        bool att = (bef / tot) < 0.5f;
        unsigned long long bits = __ballot(att);
        if (tid == 0) maskbits[h*64 + qb] = bits;
    }
}

__global__ __launch_bounds__(256, 3) void attn_v3(
    const float* __restrict__ q, const float* __restrict__ k, const float* __restrict__ v,
    const unsigned long long* __restrict__ maskbits, float* __restrict__ out)
{
    const int h = blockIdx.x >> 6, qb = blockIdx.x & 63;
    const int tid = threadIdx.x, wave = tid >> 6, lane = tid & 63;
    const int l16 = lane & 15, quad = lane >> 4;
    __shared__ __align__(16) unsigned short ks_hi[64][72];
    __shared__ __align__(16) unsigned short ks_lo[64][72];
    __shared__ __align__(16) unsigned short vt_hi[64][72];
    __shared__ __align__(16) unsigned short vt_lo[64][72];
    __shared__ __align__(16) unsigned short ps[4][16][72];

    const float4* qg = (const float4*)(q + ((size_t)h*L_ + (size_t)qb*64)*D_);
    for (int i4 = tid; i4 < 1024; i4 += 256) {
        float4 t = qg[i4];
        int r = i4 >> 4, c = (i4 & 15) << 2;
        ushort4 hi, lo;
        hi.x = f2bf(t.x); lo.x = f2bf(t.x - bf2f(hi.x));
        hi.y = f2bf(t.y); lo.y = f2bf(t.y - bf2f(hi.y));
        hi.z = f2bf(t.z); lo.z = f2bf(t.z - bf2f(hi.z));
        hi.w = f2bf(t.w); lo.w = f2bf(t.w - bf2f(hi.w));
        *(ushort4*)&ks_hi[r][c] = hi;
        *(ushort4*)&ks_lo[r][c] = lo;
    }
    const unsigned long long bm = maskbits[(h << 6) + qb];
    __syncthreads();
    bf16x8 qhi2[2], qlo2[2];
    #pragma unroll
    for (int kc = 0; kc < 2; ++kc) {
        qhi2[kc] = *(const bf16x8*)&ks_hi[wave*16 + l16][kc*32 + quad*8];
        qlo2[kc] = *(const bf16x8*)&ks_lo[wave*16 + l16][kc*32 + quad*8];
    }
    __syncthreads();
    float m_i[4], l_i[4];
    f32x4 oacc[4];
    #pragma unroll
    for (int r = 0; r < 4; ++r) { m_i[r] = -1e30f; l_i[r] = 0.f; }
    #pragma unroll
    for (int t = 0; t < 4; ++t) oacc[t] = (f32x4){0.f, 0.f, 0.f, 0.f};
    for (int kb = 0; kb < 64; ++kb) {
        if (!((bm >> kb) & 1ull)) continue;
        const float4* kg = (const float4*)(k + ((size_t)h*L_ + (size_t)kb*64)*D_);
        const float*  vg = v + ((size_t)h*L_ + (size_t)kb*64)*D_;
        for (int i4 = tid; i4 < 1024; i4 += 256) {
            float4 t = kg[i4];
            int r = i4 >> 4, c = (i4 & 15) << 2;
            ushort4 hi, lo;
            hi.x = f2bf(t.x); lo.x = f2bf(t.x - bf2f(hi.x));
            hi.y = f2bf(t.y); lo.y = f2bf(t.y - bf2f(hi.y));
            hi.z = f2bf(t.z); lo.z = f2bf(t.z - bf2f(hi.z));
            hi.w = f2bf(t.w); lo.w = f2bf(t.w - bf2f(hi.w));
            *(ushort4*)&ks_hi[r][c] = hi;
            *(ushort4*)&ks_lo[r][c] = lo;
        }
        for (int tsk = tid; tsk < 512; tsk += 256) {
            int rp = tsk >> 4;
            int c  = (tsk & 15) << 2;
            float4 a0 = *(const float4*)(vg + (size_t)(2*rp)*D_ + c);
            float4 a1 = *(const float4*)(vg + (size_t)(2*rp+1)*D_ + c);
            #pragma unroll
            for (int j = 0; j < 4; ++j) {
                float x0 = (j==0)?a0.x:(j==1)?a0.y:(j==2)?a0.z:a0.w;
                float x1 = (j==0)?a1.x:(j==1)?a1.y:(j==2)?a1.z:a1.w;
                unsigned short h0 = f2bf(x0), h1b = f2bf(x1);
                *(unsigned*)&vt_hi[c+j][2*rp] = (unsigned)h0 | ((unsigned)h1b << 16);
                unsigned short lo0 = f2bf(x0 - bf2f(h0)), lo1 = f2bf(x1 - bf2f(h1b));
                *(unsigned*)&vt_lo[c+j][2*rp] = (unsigned)lo0 | ((unsigned)lo1 << 16);
            }
        }
        __syncthreads();
        f32x4 sacc[4];
        #pragma unroll
        for (int t = 0; t < 4; ++t) sacc[t] = (f32x4){0.f, 0.f, 0.f, 0.f};
        #pragma unroll
        for (int t = 0; t < 4; ++t) {
            #pragma unroll
            for (int kc = 0; kc < 2; ++kc) {
                bf16x8 khi2 = *(const bf16x8*)&ks_hi[t*16 + l16][kc*32 + quad*8];
                bf16x8 klo2 = *(const bf16x8*)&ks_lo[t*16 + l16][kc*32 + quad*8];
                sacc[t] = __builtin_amdgcn_mfma_f32_16x16x32_bf16(qhi2[kc], khi2, sacc[t], 0, 0, 0);
                sacc[t] = __builtin_amdgcn_mfma_f32_16x16x32_bf16(qhi2[kc], klo2, sacc[t], 0, 0, 0);
                sacc[t] = __builtin_amdgcn_mfma_f32_16x16x32_bf16(qlo2[kc], khi2, sacc[t], 0, 0, 0);
            }
        }
        #pragma unroll
        for (int t = 0; t < 4; ++t) sacc[t] *= 0.125f;
        float rowmax[4];
        #pragma unroll
        for (int r = 0; r < 4; ++r)
            rowmax[r] = fmaxf(fmaxf(sacc[0][r], sacc[1][r]), fmaxf(sacc[2][r], sacc[3][r]));
        #pragma unroll
        for (int off = 1; off < 16; off <<= 1)
            #pragma unroll
            for (int r = 0; r < 4; ++r)
                rowmax[r] = fmaxf(rowmax[r], __shfl_xor(rowmax[r], off));
        float al[4], rs[4];
        #pragma unroll
        for (int r = 0; r < 4; ++r) {
            float mnew = fmaxf(m_i[r], rowmax[r]);
            al[r] = __expf(m_i[r] - mnew);
            m_i[r] = mnew;
            float acc = 0.f;
            #pragma unroll
            for (int t = 0; t < 4; ++t) {
                float p = __expf(sacc[t][r] - mnew);
                unsigned short pb = f2bf(p);
                ps[wave][quad*4 + r][t*16 + l16] = pb;
                acc += bf2f(pb);
            }
            rs[r] = acc;
        }
        #pragma unroll
        for (int off = 1; off < 16; off <<= 1)
            #pragma unroll
            for (int r = 0; r < 4; ++r)
                rs[r] += __shfl_xor(rs[r], off);
        #pragma unroll
        for (int r = 0; r < 4; ++r) l_i[r] = l_i[r] * al[r] + rs[r];
        #pragma unroll
        for (int t = 0; t < 4; ++t)
            #pragma unroll
            for (int r = 0; r < 4; ++r) oacc[t][r] *= al[r];
        bf16x8 pf[2];
        #pragma unroll
        for (int kc = 0; kc < 2; ++kc)
            pf[kc] = *(const bf16x8*)&ps[wave][l16][kc*32 + quad*8];
        #pragma unroll
        for (int t = 0; t < 4; ++t) {
            #pragma unroll
            for (int kc = 0; kc < 2; ++kc) {
                bf16x8 vhif = *(const bf16x8*)&vt_hi[t*16 + l16][kc*32 + quad*8];
                bf16x8 vlof = *(const bf16x8*)&vt_lo[t*16 + l16][kc*32 + quad*8];
                oacc[t] = __builtin_amdgcn_mfma_f32_16x16x32_bf16(pf[kc], vhif, oacc[t], 0, 0, 0);
                oacc[t] = __builtin_amdgcn_mfma_f32_16x16x32_bf16(pf[kc], vlof, oacc[t], 0, 0, 0);
            }
        }
        __syncthreads();
    }
    float* og = out + ((size_t)h*L_ + (size_t)qb*64)*D_ + (size_t)(wave*16 + quad*4)*D_;
    #pragma unroll
    for (int r = 0; r < 4; ++r) {
        float inv = 1.f / l_i[r];
        #pragma unroll
        for (int t = 0; t < 4; ++t)
            og[(size_t)r*D_ + t*16 + l16] = oacc[t][r] * inv;
    }
}

extern "C" void kernel_launch(void* const* d_in, const int* in_sizes, int n_in,
                              void* d_out, int out_size, void* d_ws, size_t ws_size,
                              hipStream_t stream) {
    const float* q = (const float*)d_in[0];
    const float* k = (const float*)d_in[1];
    const float* v = (const float*)d_in[2];
    const int* siq = (const int*)d_in[3];
    const int* sik = (const int*)d_in[4];
    float* out = (float*)d_out;

    char* ws = (char*)d_ws;
    unsigned long long* mask = (unsigned long long*)ws;          // 4 KB
    const size_t TEN = (size_t)H_*L_*D_;                         // 2,097,152 elems
    const size_t SKN = (size_t)H_*1024*64;                       //   524,288 elems
    unsigned short* qhi = (unsigned short*)(ws + 4096);
    unsigned short* qlo = qhi + TEN;
    unsigned short* khi = qlo + TEN;
    unsigned short* vth = khi + TEN;
    unsigned short* skh = vth + TEN;
    unsigned short* skl = skh + SKN;
    const size_t need = 4096 + (4*TEN + 2*SKN)*sizeof(unsigned short);  // ~18.9 MB

    if (ws_size >= need) {
        prep_kernel<<<dim3(H_*NB_), dim3(256), 0, stream>>>(q, k, v, sik, qhi, qlo, khi, vth, skh, skl);
        mask_mfma<<<dim3(H_*NB_), dim3(256), 0, stream>>>(qhi, qlo, skh, skl, siq, mask);
        attn_qsplit<<<dim3(H_*NB_), dim3(512), 0, stream>>>(qhi, khi, vth, mask, out);
    } else {
        mask_kernel4<<<dim3(H_*NB_), dim3(256), 0, stream>>>(q, k, siq, sik, mask);
        attn_v3<<<dim3(H_*NB_), dim3(256), 0, stream>>>(q, k, v, mask, out);
    }
}

// Round 9
// 137.179 us; speedup vs baseline: 1.0069x; 1.0069x over previous
//
#include <hip/hip_runtime.h>
#include <hip/hip_bf16.h>

// B=1, H=8, L=4096, D=64; 64x64 blocks; 16 samples/block. Inputs f32, output f32.
#define H_ 8
#define L_ 4096
#define D_ 64
#define NB_ 64

typedef __attribute__((ext_vector_type(8))) short bf16x8;
typedef __attribute__((ext_vector_type(4))) float f32x4;

__device__ __forceinline__ unsigned short f2bf(float x) {   // RNE f32->bf16
    unsigned u = __float_as_uint(x);
    u += 0x7fff + ((u >> 16) & 1);
    return (unsigned short)(u >> 16);
}
__device__ __forceinline__ float bf2f(unsigned short s) {
    return __uint_as_float(((unsigned)s) << 16);
}

// ---------------------------------------------------------------------------
// Preprocess (unchanged — qlo still produced for mask_mfma).
// ---------------------------------------------------------------------------
__global__ __launch_bounds__(256) void prep_kernel(
    const float* __restrict__ q, const float* __restrict__ k, const float* __restrict__ v,
    const int* __restrict__ sidxk,
    unsigned short* __restrict__ qhi, unsigned short* __restrict__ qlo,
    unsigned short* __restrict__ khi,
    unsigned short* __restrict__ vth,
    unsigned short* __restrict__ skh, unsigned short* __restrict__ skl)
{
    const int h  = blockIdx.x >> 6;
    const int tb = blockIdx.x & 63;
    const int tid = threadIdx.x;
    __shared__ float vst[64][68];

    const size_t te = ((size_t)(h*64 + tb)) << 12;   // tile base (elements)
    const float4* qg = (const float4*)(q + te);
    for (int i4 = tid; i4 < 1024; i4 += 256) {
        float4 t = qg[i4];
        ushort4 hi, lo;
        hi.x = f2bf(t.x); lo.x = f2bf(t.x - bf2f(hi.x));
        hi.y = f2bf(t.y); lo.y = f2bf(t.y - bf2f(hi.y));
        hi.z = f2bf(t.z); lo.z = f2bf(t.z - bf2f(hi.z));
        hi.w = f2bf(t.w); lo.w = f2bf(t.w - bf2f(hi.w));
        *(ushort4*)(qhi + te + i4*4) = hi;
        *(ushort4*)(qlo + te + i4*4) = lo;
    }
    const float4* kg = (const float4*)(k + te);
    for (int i4 = tid; i4 < 1024; i4 += 256) {
        float4 t = kg[i4];
        int r = i4 >> 4, c4 = i4 & 15;
        int sch = (c4 >> 1) ^ ((r >> 2) & 7);   // matches attn's permuted-key S tiles
        ushort4 hi;
        hi.x = f2bf(t.x); hi.y = f2bf(t.y); hi.z = f2bf(t.z); hi.w = f2bf(t.w);
        *(ushort4*)(khi + te + r*64 + sch*8 + (c4 & 1)*4) = hi;
    }
    // sampled-K rows for the MFMA mask
    {
        int t = tid >> 4, d4 = tid & 15;
        int srow = tb*64 + sidxk[h*16 + t];
        float4 x = *(const float4*)(k + ((size_t)h*L_ + srow)*D_ + d4*4);
        ushort4 hi, lo;
        hi.x = f2bf(x.x); lo.x = f2bf(x.x - bf2f(hi.x));
        hi.y = f2bf(x.y); lo.y = f2bf(x.y - bf2f(hi.y));
        hi.z = f2bf(x.z); lo.z = f2bf(x.z - bf2f(hi.z));
        hi.w = f2bf(x.w); lo.w = f2bf(x.w - bf2f(hi.w));
        int sch = (d4 >> 1) ^ (t & 7);
        size_t dst = ((size_t)h*1024 + tb*16 + t)*64 + sch*8 + (d4 & 1)*4;
        *(ushort4*)(skh + dst) = hi;
        *(ushort4*)(skl + dst) = lo;
    }
    const float4* vg = (const float4*)(v + te);
    for (int i4 = tid; i4 < 1024; i4 += 256) {
        float4 t = vg[i4];
        *(float4*)&vst[i4 >> 4][(i4 & 15)*4] = t;
    }
    __syncthreads();
    for (int u = tid; u < 512; u += 256) {
        int d = u >> 3, kc8 = u & 7;
        int sch = kc8 ^ (d & 7);
        ushort4 h0, h1;
        h0.x = f2bf(vst[kc8*8+0][d]); h0.y = f2bf(vst[kc8*8+1][d]);
        h0.z = f2bf(vst[kc8*8+2][d]); h0.w = f2bf(vst[kc8*8+3][d]);
        h1.x = f2bf(vst[kc8*8+4][d]); h1.y = f2bf(vst[kc8*8+5][d]);
        h1.z = f2bf(vst[kc8*8+6][d]); h1.w = f2bf(vst[kc8*8+7][d]);
        *(ushort4*)(vth + te + d*64 + sch*8 + 0) = h0;
        *(ushort4*)(vth + te + d*64 + sch*8 + 4) = h1;
    }
}

// ---------------------------------------------------------------------------
// Kernel A (v5.2): MFMA block mask. Unchanged.
// ---------------------------------------------------------------------------
__global__ __launch_bounds__(256, 4) void mask_mfma(
    const unsigned short* __restrict__ qhi, const unsigned short* __restrict__ qlo,
    const unsigned short* __restrict__ skh, const unsigned short* __restrict__ skl,
    const int* __restrict__ sidxq,
    unsigned long long* __restrict__ maskbits)
{
    const int h    = blockIdx.x & 7;    // XCD-affinity remap
    const int qb   = blockIdx.x >> 3;
    const int tid  = threadIdx.x;
    const int wave = tid >> 6;
    const int lane = tid & 63;
    const int l16  = lane & 15;
    const int quad = lane >> 4;

    __shared__ __align__(16) unsigned short ch[8192];
    __shared__ __align__(16) unsigned short cl[8192];
    __shared__ float E[16][64];
    __shared__ float Z[16];
    __shared__ float pooled[64];

    for (int e = tid; e < 16*64; e += 256) (&E[0][0])[e] = 0.f;

    const int iqr = sidxq[h*16 + l16];
    const size_t qo = (((size_t)(h*64 + qb)) << 12) + (size_t)iqr*64;
    bf16x8 qh[2], ql[2];
    qh[0] = *(const bf16x8*)(qhi + qo + quad*8);
    qh[1] = *(const bf16x8*)(qhi + qo + 32 + quad*8);
    ql[0] = *(const bf16x8*)(qlo + qo + quad*8);
    ql[1] = *(const bf16x8*)(qlo + qo + 32 + quad*8);
    __syncthreads();

    for (int cc = 0; cc < 8; ++cc) {
        const bf16x8* gh = (const bf16x8*)(skh + ((size_t)h*1024 + cc*128)*64);
        const bf16x8* gl = (const bf16x8*)(skl + ((size_t)h*1024 + cc*128)*64);
        for (int i = tid; i < 1024; i += 256) {
            ((bf16x8*)ch)[i] = gh[i];
            ((bf16x8*)cl)[i] = gl[i];
        }
        __syncthreads();

        #pragma unroll
        for (int tt = 0; tt < 2; ++tt) {
            const int kb = cc*8 + wave*2 + tt;
            const int nb = (wave*2 + tt)*16;
            f32x4 sacc = (f32x4){0.f, 0.f, 0.f, 0.f};
            #pragma unroll
            for (int kc = 0; kc < 2; ++kc) {
                const int off = (nb + l16)*64 + (((kc*4 + quad) ^ (l16 & 7))*8);
                bf16x8 kh = *(const bf16x8*)&ch[off];
                bf16x8 kl = *(const bf16x8*)&cl[off];
                sacc = __builtin_amdgcn_mfma_f32_16x16x32_bf16(qh[kc], kh, sacc, 0, 0, 0);
                sacc = __builtin_amdgcn_mfma_f32_16x16x32_bf16(qh[kc], kl, sacc, 0, 0, 0);
                sacc = __builtin_amdgcn_mfma_f32_16x16x32_bf16(ql[kc], kh, sacc, 0, 0, 0);
                sacc = __builtin_amdgcn_mfma_f32_16x16x32_bf16(ql[kc], kl, sacc, 0, 0, 0);
            }
            #pragma unroll
            for (int r = 0; r < 4; ++r) {
                float p = __expf(sacc[r] * 0.125f);
                p += __shfl_xor(p, 1);
                p += __shfl_xor(p, 2);
                p += __shfl_xor(p, 4);
                p += __shfl_xor(p, 8);
                if (l16 == 0) E[quad*4 + r][kb] = p;
            }
        }
        __syncthreads();
    }

    if (tid < 16) {
        float s = 0.f;
        #pragma unroll
        for (int kb = 0; kb < 64; ++kb) s += E[tid][kb];
        Z[tid] = s;
    }
    __syncthreads();
    if (tid < 64) {
        float s = 0.f;
        #pragma unroll
        for (int t = 0; t < 16; ++t) s += E[t][tid] / Z[t];
        pooled[tid] = s;
    }
    __syncthreads();
    if (tid < 64) {
        float pi = pooled[tid];
        float tot = 0.f, bef = 0.f;
        for (int j2 = 0; j2 < 64; ++j2) {
            float pj = pooled[j2];
            tot += pj;
            if (pj > pi || (pj == pi && j2 < tid)) bef += pj;
        }
        bool att = (bef / tot) < 0.5f;
        unsigned long long bits = __ballot(att);
        if (tid == 0) maskbits[h*64 + qb] = bits;
    }
}

// ---------------------------------------------------------------------------
// Kernel B (v15): q-half split, 4-wave blocks, 3 waves/SIMD (de-confounded).
// ROUND 19. R8 regressed with TWO confounds: forced 128-VGPR cap below true
// pressure (~140 -> inner-loop spills) AND doubled K/V loads. This round
// repeats the occupancy bet cleanly at 3 waves/SIMD (129-170 VGPR band):
//  - 256-thr blocks: waves {0,1} q-rows 0-31, waves {2,3} rows 32-63;
//    within a half, waves stride attended k-blocks 2-way (kw = wave&1).
//  - Per-wave regs: oacc 32 + lacc 8 + kf 32 + vf 32 (separate, v13's proven
//    prefetch schedule, no time-share) + temps ~= 140 <= 170 cap -> no spills.
//  - LDS 33.3KB (Qh 9.2K + ps 4x5.5K; reduce 32.8K union) -> LDS allows 4;
//    VGPR band gives 3 blocks/CU = 12 waves/CU = 3/SIMD (was 2).
//  - launch_bounds(256,3). Per-tile math identical to v13; reduce combines
//    2 partials/row (R12 class). K/V L2 traffic x2 (isolates R8's spill
//    confound: flat result here = occupancy conclusively not the lever).
// ---------------------------------------------------------------------------
__global__ __launch_bounds__(256, 3) void attn_qh(
    const unsigned short* __restrict__ qhi,
    const unsigned short* __restrict__ khi,
    const unsigned short* __restrict__ vth,
    const unsigned long long* __restrict__ maskbits,
    float* __restrict__ out)
{
    const int h    = blockIdx.x & 7;    // XCD-affinity remap
    const int qb   = blockIdx.x >> 3;
    const int tid  = threadIdx.x;
    const int wave = tid >> 6;
    const int lane = tid & 63;
    const int l16  = lane & 15;
    const int quad = lane >> 4;
    const int qhalf = wave >> 1;        // q-rows qhalf*32 .. +31
    const int kw    = wave & 1;         // k-stride rank within the half

    // LDS union: stream = Qh[64][72] (9216B) + ps[4 waves][32][88] (22528B)
    //            reduce = ored[2][64][64] f32 (32768B) + lred[2][64] (512B)
    __shared__ __align__(16) char SM[33280];
    unsigned short* Qh = (unsigned short*)SM;                         // [64][72]
    unsigned short* ps = (unsigned short*)(SM + 9216 + wave*5632);    // [32][88]

    const size_t qbase = ((size_t)(h*64 + qb)) << 12;

    // ---- stage swizzled Q (hi) to LDS, shared by all waves ----
    for (int c = tid; c < 512; c += 256) {
        int row = c >> 3, cc = c & 7;
        int sw = cc ^ ((row >> 2) & 7);
        *(uint4*)&Qh[row*72 + sw*8] = *(const uint4*)(qhi + qbase + row*64 + cc*8);
    }

    // ---- my k-block list: every 2nd set bit, starting at rank kw ----
    unsigned long long rem = maskbits[(h << 6) + qb];
    if (kw && rem) rem &= rem - 1;
    int cur = rem ? (int)__builtin_ctzll(rem) : -1;

    const bf16x8 ones = {0x3F80, 0x3F80, 0x3F80, 0x3F80, 0x3F80, 0x3F80, 0x3F80, 0x3F80};

    f32x4 lacc[2];
    f32x4 oacc[2][4];
    #pragma unroll
    for (int qt = 0; qt < 2; ++qt) {
        lacc[qt] = (f32x4){0.f, 0.f, 0.f, 0.f};
        #pragma unroll
        for (int dt = 0; dt < 4; ++dt) oacc[qt][dt] = (f32x4){0.f, 0.f, 0.f, 0.f};
    }

    bf16x8 kf[4][2], vf[4][2];
    if (cur >= 0) {      // first-tile loads issued before the Q barrier (overlap)
        const size_t tb = ((size_t)(h*64 + cur)) << 12;
        #pragma unroll
        for (int t = 0; t < 4; ++t)
            #pragma unroll
            for (int kc = 0; kc < 2; ++kc) {
                kf[t][kc] = *(const bf16x8*)(khi + tb + (l16*4 + t)*64 + (((kc*4 + quad) ^ (l16 & 7))*8));
                vf[t][kc] = *(const bf16x8*)(vth + tb + (t*16 + l16)*64 + (((kc*4 + quad) ^ (l16 & 7))*8));
            }
    }
    __syncthreads();   // Q published

    while (cur >= 0) {
        rem &= rem - 1; rem &= rem - 1;                     // pop 2 (0-safe)
        const int nxt = rem ? (int)__builtin_ctzll(rem) : -1;

        // ---- QK + fixed-M softmax, my 2 q-tiles ----
        #pragma unroll
        for (int lqt = 0; lqt < 2; ++lqt) {
            const int gqt = qhalf*2 + lqt;
            const int xb = (gqt*4 + (l16 >> 2)) & 7;
            bf16x8 ah[2];
            #pragma unroll
            for (int kc = 0; kc < 2; ++kc)
                ah[kc] = *(const bf16x8*)&Qh[(gqt*16 + l16)*72 + (((kc*4 + quad) ^ xb)*8)];
            f32x4 sacc[4];
            #pragma unroll
            for (int t = 0; t < 4; ++t) {
                f32x4 s = (f32x4){0.f, 0.f, 0.f, 0.f};
                s = __builtin_amdgcn_mfma_f32_16x16x32_bf16(ah[0], kf[t][0], s, 0, 0, 0);
                s = __builtin_amdgcn_mfma_f32_16x16x32_bf16(ah[1], kf[t][1], s, 0, 0, 0);
                sacc[t] = s;
            }
            // p = exp(s*0.125 - 16) = exp2(fma(s, 0.125*log2e, -16*log2e))
            #pragma unroll
            for (int r = 0; r < 4; ++r) {
                float p0 = __builtin_amdgcn_exp2f(fmaf(sacc[0][r], 0.18033688f, -23.083121f));
                float p1 = __builtin_amdgcn_exp2f(fmaf(sacc[1][r], 0.18033688f, -23.083121f));
                float p2 = __builtin_amdgcn_exp2f(fmaf(sacc[2][r], 0.18033688f, -23.083121f));
                float p3 = __builtin_amdgcn_exp2f(fmaf(sacc[3][r], 0.18033688f, -23.083121f));
                __hip_bfloat162 a01 = __float22bfloat162_rn(make_float2(p0, p1));
                __hip_bfloat162 a23 = __float22bfloat162_rn(make_float2(p2, p3));
                uint2 w; w.x = *(unsigned*)&a01; w.y = *(unsigned*)&a23;
                *(uint2*)&ps[(lqt*16 + quad*4 + r)*88 + l16*4] = w;
            }
        }
        // ---- prefetch next K (kf free after QK; covered by SM+PV) ----
        if (nxt >= 0) {
            const size_t tb = ((size_t)(h*64 + nxt)) << 12;
            #pragma unroll
            for (int t = 0; t < 4; ++t)
                #pragma unroll
                for (int kc = 0; kc < 2; ++kc)
                    kf[t][kc] = *(const bf16x8*)(khi + tb + (l16*4 + t)*64 + (((kc*4 + quad) ^ (l16 & 7))*8));
        }
        // ---- PV + l-rowsum (ones-MFMA), ps wave-local ----
        #pragma unroll
        for (int lqt = 0; lqt < 2; ++lqt) {
            bf16x8 pf0 = *(const bf16x8*)&ps[(lqt*16 + l16)*88 + quad*8];
            bf16x8 pf1 = *(const bf16x8*)&ps[(lqt*16 + l16)*88 + 32 + quad*8];
            lacc[lqt] = __builtin_amdgcn_mfma_f32_16x16x32_bf16(pf0, ones, lacc[lqt], 0, 0, 0);
            lacc[lqt] = __builtin_amdgcn_mfma_f32_16x16x32_bf16(pf1, ones, lacc[lqt], 0, 0, 0);
            #pragma unroll
            for (int dt = 0; dt < 4; ++dt) {
                oacc[lqt][dt] = __builtin_amdgcn_mfma_f32_16x16x32_bf16(pf0, vf[dt][0], oacc[lqt][dt], 0, 0, 0);
                oacc[lqt][dt] = __builtin_amdgcn_mfma_f32_16x16x32_bf16(pf1, vf[dt][1], oacc[lqt][dt], 0, 0, 0);
            }
        }
        // ---- prefetch next V (vf free after PV; covered by next QK) ----
        if (nxt >= 0) {
            const size_t tb = ((size_t)(h*64 + nxt)) << 12;
            #pragma unroll
            for (int dt = 0; dt < 4; ++dt)
                #pragma unroll
                for (int kc = 0; kc < 2; ++kc)
                    vf[dt][kc] = *(const bf16x8*)(vth + tb + (dt*16 + l16)*64 + (((kc*4 + quad) ^ (l16 & 7))*8));
        }
        cur = nxt;
    }

    // ---- cross-wave reduce: O = sum_kw O / sum_kw l ----
    __syncthreads();   // stream LDS dead
    float* ored = (float*)SM;            // [2][64][64]
    float* lred = (float*)(SM + 32768);  // [2][64]
    #pragma unroll
    for (int lqt = 0; lqt < 2; ++lqt) {
        const int gr0 = qhalf*32 + lqt*16 + quad*4;
        #pragma unroll
        for (int dt = 0; dt < 4; ++dt)
            #pragma unroll
            for (int r = 0; r < 4; ++r)
                ored[(kw*64 + gr0 + r)*64 + dt*16 + l16] = oacc[lqt][dt][r];
        if (l16 == 0) {
            #pragma unroll
            for (int r = 0; r < 4; ++r)
                lred[kw*64 + gr0 + r] = lacc[lqt][r];
        }
    }
    __syncthreads();
    {
        const int row = tid >> 2;
        const int d0  = (tid & 3) << 4;
        float l = lred[row] + lred[64 + row];
        float inv = 1.f / l;
        float* og = out + ((size_t)h*L_ + (size_t)qb*64 + row)*D_ + d0;
        #pragma unroll
        for (int j = 0; j < 16; j += 4) {
            float4 a = *(float4*)&ored[row*64 + d0 + j];
            float4 b = *(float4*)&ored[4096 + row*64 + d0 + j];
            float4 rr;
            rr.x = (a.x + b.x) * inv;
            rr.y = (a.y + b.y) * inv;
            rr.z = (a.z + b.z) * inv;
            rr.w = (a.w + b.w) * inv;
            *(float4*)(og + j) = rr;
        }
    }
}

// ---------------------------------------------------------------------------
// Fallback path (round-6, proven): mask_kernel4 + attn_v3, only if ws small.
// ---------------------------------------------------------------------------
__global__ __launch_bounds__(256, 4) void mask_kernel4(
    const float* __restrict__ q, const float* __restrict__ k,
    const int* __restrict__ sidxq, const int* __restrict__ sidxk,
    unsigned long long* __restrict__ maskbits)
{
    const int h   = blockIdx.x >> 6;
    const int qb  = blockIdx.x & 63;
    const int tid = threadIdx.x;
    const int rg  = tid >> 5;
    const int cg  = tid & 31;

    __shared__ float sq[16][68];
    __shared__ float skc[128][68];
    __shared__ float E[16][64];
    __shared__ float Z[16];
    __shared__ float pooled[64];
    __shared__ int iq[16], ik[16];

    if (tid < 16) { iq[tid] = sidxq[h*16 + tid]; ik[tid] = sidxk[h*16 + tid]; }
    for (int e = tid; e < 16*64; e += 256) (&E[0][0])[e] = 0.f;
    __syncthreads();
    {
        int j = tid >> 4, d4 = tid & 15;
        int grow = h*L_ + qb*64 + iq[j];
        *(float4*)&sq[j][d4*4] = *(const float4*)(q + (size_t)grow*D_ + d4*4);
    }
    for (int cc = 0; cc < 8; ++cc) {
        for (int i = tid; i < 2048; i += 256) {
            int col = i >> 4, d4 = i & 15;
            int colg = cc*128 + col;
            int grow = h*L_ + (colg >> 4)*64 + ik[colg & 15];
            *(float4*)&skc[col][d4*4] = *(const float4*)(k + (size_t)grow*D_ + d4*4);
        }
        __syncthreads();
        float acc[2][4] = {{0.f,0.f,0.f,0.f},{0.f,0.f,0.f,0.f}};
        #pragma unroll 4
        for (int d4 = 0; d4 < 16; ++d4) {
            float4 qv0 = *(const float4*)&sq[rg*2 + 0][d4*4];
            float4 qv1 = *(const float4*)&sq[rg*2 + 1][d4*4];
            #pragma unroll
            for (int j = 0; j < 4; ++j) {
                float4 kv = *(const float4*)&skc[cg + 32*j][d4*4];
                acc[0][j] += qv0.x*kv.x + qv0.y*kv.y + qv0.z*kv.z + qv0.w*kv.w;
                acc[1][j] += qv1.x*kv.x + qv1.y*kv.y + qv1.z*kv.z + qv1.w*kv.w;
            }
        }
        #pragma unroll
        for (int j = 0; j < 4; ++j) {
            int kb = cc*8 + (cg >> 4) + 2*j;
            #pragma unroll
            for (int i = 0; i < 2; ++i) {
                float p = __expf(acc[i][j] * 0.125f);
                p += __shfl_xor(p, 1);
                p += __shfl_xor(p, 2);
                p += __shfl_xor(p, 4);
                p += __shfl_xor(p, 8);
                if ((cg & 15) == 0) E[rg*2 + i][kb] += p;
            }
        }
        __syncthreads();
    }
    if (tid < 16) {
        float s = 0.f;
        #pragma unroll
        for (int kb = 0; kb < 64; ++kb) s += E[tid][kb];
        Z[tid] = s;
    }
    __syncthreads();
    if (tid < 64) {
        float s = 0.f;
        #pragma unroll
        for (int t = 0; t < 16; ++t) s += E[t][tid] / Z[t];
        pooled[tid] = s;
    }
    __syncthreads();
    if (tid < 64) {
        float pi = pooled[tid];
        float tot = 0.f, bef = 0.f;
        for (int j2 = 0; j2 < 64; ++j2) {
            float pj = pooled[j2];
            tot += pj;
            if (pj > pi || (pj == pi && j2 < tid)) bef += pj;
        }
        bool att = (bef / tot) < 0.5f;
        unsigned long long bits = __ballot(att);
        if (tid == 0) maskbits[h*64 + qb] = bits;
    }
}

__global__ __launch_bounds__(256, 3) void attn_v3(
    const float* __restrict__ q, const float* __restrict__ k, const float* __restrict__ v,
    const unsigned long long* __restrict__ maskbits, float* __restrict__ out)
{
    const int h = blockIdx.x >> 6, qb = blockIdx.x & 63;
    const int tid = threadIdx.x, wave = tid >> 6, lane = tid & 63;
    const int l16 = lane & 15, quad = lane >> 4;
    __shared__ __align__(16) unsigned short ks_hi[64][72];
    __shared__ __align__(16) unsigned short ks_lo[64][72];
    __shared__ __align__(16) unsigned short vt_hi[64][72];
    __shared__ __align__(16) unsigned short vt_lo[64][72];
    __shared__ __align__(16) unsigned short ps[4][16][72];

    const float4* qg = (const float4*)(q + ((size_t)h*L_ + (size_t)qb*64)*D_);
    for (int i4 = tid; i4 < 1024; i4 += 256) {
        float4 t = qg[i4];
        int r = i4 >> 4, c = (i4 & 15) << 2;
        ushort4 hi, lo;
        hi.x = f2bf(t.x); lo.x = f2bf(t.x - bf2f(hi.x));
        hi.y = f2bf(t.y); lo.y = f2bf(t.y - bf2f(hi.y));
        hi.z = f2bf(t.z); lo.z = f2bf(t.z - bf2f(hi.z));
        hi.w = f2bf(t.w); lo.w = f2bf(t.w - bf2f(hi.w));
        *(ushort4*)&ks_hi[r][c] = hi;
        *(ushort4*)&ks_lo[r][c] = lo;
    }
    const unsigned long long bm = maskbits[(h << 6) + qb];
    __syncthreads();
    bf16x8 qhi2[2], qlo2[2];
    #pragma unroll
    for (int kc = 0; kc < 2; ++kc) {
        qhi2[kc] = *(const bf16x8*)&ks_hi[wave*16 + l16][kc*32 + quad*8];
        qlo2[kc] = *(const bf16x8*)&ks_lo[wave*16 + l16][kc*32 + quad*8];
    }
    __syncthreads();
    float m_i[4], l_i[4];
    f32x4 oacc[4];
    #pragma unroll
    for (int r = 0; r < 4; ++r) { m_i[r] = -1e30f; l_i[r] = 0.f; }
    #pragma unroll
    for (int t = 0; t < 4; ++t) oacc[t] = (f32x4){0.f, 0.f, 0.f, 0.f};
    for (int kb = 0; kb < 64; ++kb) {
        if (!((bm >> kb) & 1ull)) continue;
        const float4* kg = (const float4*)(k + ((size_t)h*L_ + (size_t)kb*64)*D_);
        const float*  vg = v + ((size_t)h*L_ + (size_t)kb*64)*D_;
        for (int i4 = tid; i4 < 1024; i4 += 256) {
            float4 t = kg[i4];
            int r = i4 >> 4, c = (i4 & 15) << 2;
            ushort4 hi, lo;
            hi.x = f2bf(t.x); lo.x = f2bf(t.x - bf2f(hi.x));
            hi.y = f2bf(t.y); lo.y = f2bf(t.y - bf2f(hi.y));
            hi.z = f2bf(t.z); lo.z = f2bf(t.z - bf2f(hi.z));
            hi.w = f2bf(t.w); lo.w = f2bf(t.w - bf2f(hi.w));
            *(ushort4*)&ks_hi[r][c] = hi;
            *(ushort4*)&ks_lo[r][c] = lo;
        }
        for (int tsk = tid; tsk < 512; tsk += 256) {
            int rp = tsk >> 4;
            int c  = (tsk & 15) << 2;
            float4 a0 = *(const float4*)(vg + (size_t)(2*rp)*D_ + c);
            float4 a1 = *(const float4*)(vg + (size_t)(2*rp+1)*D_ + c);
            #pragma unroll
            for (int j = 0; j < 4; ++j) {
                float x0 = (j==0)?a0.x:(j==1)?a0.y:(j==2)?a0.z:a0.w;
                float x1 = (j==0)?a1.x:(j==1)?a1.y:(j==2)?a1.z:a1.w;
                unsigned short h0 = f2bf(x0), h1b = f2bf(x1);
                *(unsigned*)&vt_hi[c+j][2*rp] = (unsigned)h0 | ((unsigned)h1b << 16);
                unsigned short lo0 = f2bf(x0 - bf2f(h0)), lo1 = f2bf(x1 - bf2f(h1b));
                *(unsigned*)&vt_lo[c+j][2*rp] = (unsigned)lo0 | ((unsigned)lo1 << 16);
            }
        }
        __syncthreads();
        f32x4 sacc[4];
        #pragma unroll
        for (int t = 0; t < 4; ++t) sacc[t] = (f32x4){0.f, 0.f, 0.f, 0.f};
        #pragma unroll
        for (int t = 0; t < 4; ++t) {
            #pragma unroll
            for (int kc = 0; kc < 2; ++kc) {
                bf16x8 khi2 = *(const bf16x8*)&ks_hi[t*16 + l16][kc*32 + quad*8];
                bf16x8 klo2 = *(const bf16x8*)&ks_lo[t*16 + l16][kc*32 + quad*8];
                sacc[t] = __builtin_amdgcn_mfma_f32_16x16x32_bf16(qhi2[kc], khi2, sacc[t], 0, 0, 0);
                sacc[t] = __builtin_amdgcn_mfma_f32_16x16x32_bf16(qhi2[kc], klo2, sacc[t], 0, 0, 0);
                sacc[t] = __builtin_amdgcn_mfma_f32_16x16x32_bf16(qlo2[kc], khi2, sacc[t], 0, 0, 0);
            }
        }
        #pragma unroll
        for (int t = 0; t < 4; ++t) sacc[t] *= 0.125f;
        float rowmax[4];
        #pragma unroll
        for (int r = 0; r < 4; ++r)
            rowmax[r] = fmaxf(fmaxf(sacc[0][r], sacc[1][r]), fmaxf(sacc[2][r], sacc[3][r]));
        #pragma unroll
        for (int off = 1; off < 16; off <<= 1)
            #pragma unroll
            for (int r = 0; r < 4; ++r)
                rowmax[r] = fmaxf(rowmax[r], __shfl_xor(rowmax[r], off));
        float al[4], rs[4];
        #pragma unroll
        for (int r = 0; r < 4; ++r) {
            float mnew = fmaxf(m_i[r], rowmax[r]);
            al[r] = __expf(m_i[r] - mnew);
            m_i[r] = mnew;
            float acc = 0.f;
            #pragma unroll
            for (int t = 0; t < 4; ++t) {
                float p = __expf(sacc[t][r] - mnew);
                unsigned short pb = f2bf(p);
                ps[wave][quad*4 + r][t*16 + l16] = pb;
                acc += bf2f(pb);
            }
            rs[r] = acc;
        }
        #pragma unroll
        for (int off = 1; off < 16; off <<= 1)
            #pragma unroll
            for (int r = 0; r < 4; ++r)
                rs[r] += __shfl_xor(rs[r], off);
        #pragma unroll
        for (int r = 0; r < 4; ++r) l_i[r] = l_i[r] * al[r] + rs[r];
        #pragma unroll
        for (int t = 0; t < 4; ++t)
            #pragma unroll
            for (int r = 0; r < 4; ++r) oacc[t][r] *= al[r];
        bf16x8 pf[2];
        #pragma unroll
        for (int kc = 0; kc < 2; ++kc)
            pf[kc] = *(const bf16x8*)&ps[wave][l16][kc*32 + quad*8];
        #pragma unroll
        for (int t = 0; t < 4; ++t) {
            #pragma unroll
            for (int kc = 0; kc < 2; ++kc) {
                bf16x8 vhif = *(const bf16x8*)&vt_hi[t*16 + l16][kc*32 + quad*8];
                bf16x8 vlof = *(const bf16x8*)&vt_lo[t*16 + l16][kc*32 + quad*8];
                oacc[t] = __builtin_amdgcn_mfma_f32_16x16x32_bf16(pf[kc], vhif, oacc[t], 0, 0, 0);
                oacc[t] = __builtin_amdgcn_mfma_f32_16x16x32_bf16(pf[kc], vlof, oacc[t], 0, 0, 0);
            }
        }
        __syncthreads();
    }
    float* og = out + ((size_t)h*L_ + (size_t)qb*64)*D_ + (size_t)(wave*16 + quad*4)*D_;
    #pragma unroll
    for (int r = 0; r < 4; ++r) {
        float inv = 1.f / l_i[r];
        #pragma unroll
        for (int t = 0; t < 4; ++t)
            og[(size_t)r*D_ + t*16 + l16] = oacc[t][r] * inv;
    }
}

extern "C" void kernel_launch(void* const* d_in, const int* in_sizes, int n_in,
                              void* d_out, int out_size, void* d_ws, size_t ws_size,
                              hipStream_t stream) {
    const float* q = (const float*)d_in[0];
    const float* k = (const float*)d_in[1];
    const float* v = (const float*)d_in[2];
    const int* siq = (const int*)d_in[3];
    const int* sik = (const int*)d_in[4];
    float* out = (float*)d_out;

    char* ws = (char*)d_ws;
    unsigned long long* mask = (unsigned long long*)ws;          // 4 KB
    const size_t TEN = (size_t)H_*L_*D_;                         // 2,097,152 elems
    const size_t SKN = (size_t)H_*1024*64;                       //   524,288 elems
    unsigned short* qhi = (unsigned short*)(ws + 4096);
    unsigned short* qlo = qhi + TEN;
    unsigned short* khi = qlo + TEN;
    unsigned short* vth = khi + TEN;
    unsigned short* skh = vth + TEN;
    unsigned short* skl = skh + SKN;
    const size_t need = 4096 + (4*TEN + 2*SKN)*sizeof(unsigned short);  // ~18.9 MB

    if (ws_size >= need) {
        prep_kernel<<<dim3(H_*NB_), dim3(256), 0, stream>>>(q, k, v, sik, qhi, qlo, khi, vth, skh, skl);
        mask_mfma<<<dim3(H_*NB_), dim3(256), 0, stream>>>(qhi, qlo, skh, skl, siq, mask);
        attn_qh<<<dim3(H_*NB_), dim3(256), 0, stream>>>(qhi, khi, vth, mask, out);
    } else {
        mask_kernel4<<<dim3(H_*NB_), dim3(256), 0, stream>>>(q, k, siq, sik, mask);
        attn_v3<<<dim3(H_*NB_), dim3(256), 0, stream>>>(q, k, v, mask, out);
    }
}

// Round 10
// 134.692 us; speedup vs baseline: 1.0255x; 1.0185x over previous
//
#include <hip/hip_runtime.h>
#include <hip/hip_bf16.h>

// B=1, H=8, L=4096, D=64; 64x64 blocks; 16 samples/block. Inputs f32, output f32.
#define H_ 8
#define L_ 4096
#define D_ 64
#define NB_ 64

typedef __attribute__((ext_vector_type(8))) short bf16x8;
typedef __attribute__((ext_vector_type(4))) float f32x4;

__device__ __forceinline__ unsigned short f2bf(float x) {   // RNE f32->bf16
    unsigned u = __float_as_uint(x);
    u += 0x7fff + ((u >> 16) & 1);
    return (unsigned short)(u >> 16);
}
__device__ __forceinline__ float bf2f(unsigned short s) {
    return __uint_as_float(((unsigned)s) << 16);
}

// ---------------------------------------------------------------------------
// Preprocess (unchanged — qlo still produced for mask_mfma).
// ---------------------------------------------------------------------------
__global__ __launch_bounds__(256) void prep_kernel(
    const float* __restrict__ q, const float* __restrict__ k, const float* __restrict__ v,
    const int* __restrict__ sidxk,
    unsigned short* __restrict__ qhi, unsigned short* __restrict__ qlo,
    unsigned short* __restrict__ khi,
    unsigned short* __restrict__ vth,
    unsigned short* __restrict__ skh, unsigned short* __restrict__ skl)
{
    const int h  = blockIdx.x >> 6;
    const int tb = blockIdx.x & 63;
    const int tid = threadIdx.x;
    __shared__ float vst[64][68];

    const size_t te = ((size_t)(h*64 + tb)) << 12;   // tile base (elements)
    const float4* qg = (const float4*)(q + te);
    for (int i4 = tid; i4 < 1024; i4 += 256) {
        float4 t = qg[i4];
        ushort4 hi, lo;
        hi.x = f2bf(t.x); lo.x = f2bf(t.x - bf2f(hi.x));
        hi.y = f2bf(t.y); lo.y = f2bf(t.y - bf2f(hi.y));
        hi.z = f2bf(t.z); lo.z = f2bf(t.z - bf2f(hi.z));
        hi.w = f2bf(t.w); lo.w = f2bf(t.w - bf2f(hi.w));
        *(ushort4*)(qhi + te + i4*4) = hi;
        *(ushort4*)(qlo + te + i4*4) = lo;
    }
    const float4* kg = (const float4*)(k + te);
    for (int i4 = tid; i4 < 1024; i4 += 256) {
        float4 t = kg[i4];
        int r = i4 >> 4, c4 = i4 & 15;
        int sch = (c4 >> 1) ^ ((r >> 2) & 7);   // matches attn's permuted-key S tiles
        ushort4 hi;
        hi.x = f2bf(t.x); hi.y = f2bf(t.y); hi.z = f2bf(t.z); hi.w = f2bf(t.w);
        *(ushort4*)(khi + te + r*64 + sch*8 + (c4 & 1)*4) = hi;
    }
    // sampled-K rows for the MFMA mask
    {
        int t = tid >> 4, d4 = tid & 15;
        int srow = tb*64 + sidxk[h*16 + t];
        float4 x = *(const float4*)(k + ((size_t)h*L_ + srow)*D_ + d4*4);
        ushort4 hi, lo;
        hi.x = f2bf(x.x); lo.x = f2bf(x.x - bf2f(hi.x));
        hi.y = f2bf(x.y); lo.y = f2bf(x.y - bf2f(hi.y));
        hi.z = f2bf(x.z); lo.z = f2bf(x.z - bf2f(hi.z));
        hi.w = f2bf(x.w); lo.w = f2bf(x.w - bf2f(hi.w));
        int sch = (d4 >> 1) ^ (t & 7);
        size_t dst = ((size_t)h*1024 + tb*16 + t)*64 + sch*8 + (d4 & 1)*4;
        *(ushort4*)(skh + dst) = hi;
        *(ushort4*)(skl + dst) = lo;
    }
    const float4* vg = (const float4*)(v + te);
    for (int i4 = tid; i4 < 1024; i4 += 256) {
        float4 t = vg[i4];
        *(float4*)&vst[i4 >> 4][(i4 & 15)*4] = t;
    }
    __syncthreads();
    for (int u = tid; u < 512; u += 256) {
        int d = u >> 3, kc8 = u & 7;
        int sch = kc8 ^ (d & 7);
        ushort4 h0, h1;
        h0.x = f2bf(vst[kc8*8+0][d]); h0.y = f2bf(vst[kc8*8+1][d]);
        h0.z = f2bf(vst[kc8*8+2][d]); h0.w = f2bf(vst[kc8*8+3][d]);
        h1.x = f2bf(vst[kc8*8+4][d]); h1.y = f2bf(vst[kc8*8+5][d]);
        h1.z = f2bf(vst[kc8*8+6][d]); h1.w = f2bf(vst[kc8*8+7][d]);
        *(ushort4*)(vth + te + d*64 + sch*8 + 0) = h0;
        *(ushort4*)(vth + te + d*64 + sch*8 + 4) = h1;
    }
}

// ---------------------------------------------------------------------------
// Kernel A (v5.2): MFMA block mask. Unchanged.
// ---------------------------------------------------------------------------
__global__ __launch_bounds__(256, 4) void mask_mfma(
    const unsigned short* __restrict__ qhi, const unsigned short* __restrict__ qlo,
    const unsigned short* __restrict__ skh, const unsigned short* __restrict__ skl,
    const int* __restrict__ sidxq,
    unsigned long long* __restrict__ maskbits)
{
    const int h    = blockIdx.x & 7;    // XCD-affinity remap
    const int qb   = blockIdx.x >> 3;
    const int tid  = threadIdx.x;
    const int wave = tid >> 6;
    const int lane = tid & 63;
    const int l16  = lane & 15;
    const int quad = lane >> 4;

    __shared__ __align__(16) unsigned short ch[8192];
    __shared__ __align__(16) unsigned short cl[8192];
    __shared__ float E[16][64];
    __shared__ float Z[16];
    __shared__ float pooled[64];

    for (int e = tid; e < 16*64; e += 256) (&E[0][0])[e] = 0.f;

    const int iqr = sidxq[h*16 + l16];
    const size_t qo = (((size_t)(h*64 + qb)) << 12) + (size_t)iqr*64;
    bf16x8 qh[2], ql[2];
    qh[0] = *(const bf16x8*)(qhi + qo + quad*8);
    qh[1] = *(const bf16x8*)(qhi + qo + 32 + quad*8);
    ql[0] = *(const bf16x8*)(qlo + qo + quad*8);
    ql[1] = *(const bf16x8*)(qlo + qo + 32 + quad*8);
    __syncthreads();

    for (int cc = 0; cc < 8; ++cc) {
        const bf16x8* gh = (const bf16x8*)(skh + ((size_t)h*1024 + cc*128)*64);
        const bf16x8* gl = (const bf16x8*)(skl + ((size_t)h*1024 + cc*128)*64);
        for (int i = tid; i < 1024; i += 256) {
            ((bf16x8*)ch)[i] = gh[i];
            ((bf16x8*)cl)[i] = gl[i];
        }
        __syncthreads();

        #pragma unroll
        for (int tt = 0; tt < 2; ++tt) {
            const int kb = cc*8 + wave*2 + tt;
            const int nb = (wave*2 + tt)*16;
            f32x4 sacc = (f32x4){0.f, 0.f, 0.f, 0.f};
            #pragma unroll
            for (int kc = 0; kc < 2; ++kc) {
                const int off = (nb + l16)*64 + (((kc*4 + quad) ^ (l16 & 7))*8);
                bf16x8 kh = *(const bf16x8*)&ch[off];
                bf16x8 kl = *(const bf16x8*)&cl[off];
                sacc = __builtin_amdgcn_mfma_f32_16x16x32_bf16(qh[kc], kh, sacc, 0, 0, 0);
                sacc = __builtin_amdgcn_mfma_f32_16x16x32_bf16(qh[kc], kl, sacc, 0, 0, 0);
                sacc = __builtin_amdgcn_mfma_f32_16x16x32_bf16(ql[kc], kh, sacc, 0, 0, 0);
                sacc = __builtin_amdgcn_mfma_f32_16x16x32_bf16(ql[kc], kl, sacc, 0, 0, 0);
            }
            #pragma unroll
            for (int r = 0; r < 4; ++r) {
                float p = __expf(sacc[r] * 0.125f);
                p += __shfl_xor(p, 1);
                p += __shfl_xor(p, 2);
                p += __shfl_xor(p, 4);
                p += __shfl_xor(p, 8);
                if (l16 == 0) E[quad*4 + r][kb] = p;
            }
        }
        __syncthreads();
    }

    if (tid < 16) {
        float s = 0.f;
        #pragma unroll
        for (int kb = 0; kb < 64; ++kb) s += E[tid][kb];
        Z[tid] = s;
    }
    __syncthreads();
    if (tid < 64) {
        float s = 0.f;
        #pragma unroll
        for (int t = 0; t < 16; ++t) s += E[t][tid] / Z[t];
        pooled[tid] = s;
    }
    __syncthreads();
    if (tid < 64) {
        float pi = pooled[tid];
        float tot = 0.f, bef = 0.f;
        for (int j2 = 0; j2 < 64; ++j2) {
            float pj = pooled[j2];
            tot += pj;
            if (pj > pi || (pj == pi && j2 < tid)) bef += pj;
        }
        bool att = (bef / tot) < 0.5f;
        unsigned long long bits = __ballot(att);
        if (tid == 0) maskbits[h*64 + qb] = bits;
    }
}

// ---------------------------------------------------------------------------
// Kernel B (v13.1): WAVE-PRIVATE flash attention, bf16-only Q + setprio.
// ROUND 20. R9 (3 waves/SIMD, de-confounded) was a clean null -> occupancy
// conclusively not the lever for the wave-independent structure; per-wave
// issue+chain cost is the wall (issue floor ~19us, measured ~31us, 62%
// packed). Revert to the 133.4us v13 config; the one mechanism-backed
// residual lever is s_setprio(1) around the QK and PV MFMA clusters --
// our waves are INDEPENDENT (m191's regime: +4-7% on attn; null only in
// barrier-gang lockstep), so the CU scheduler can prefer an MFMA-entering
// wave over its SM-phase sibling. Everything else byte-identical to R7.
// ---------------------------------------------------------------------------
__global__ __launch_bounds__(256, 2) void attn_wave(
    const unsigned short* __restrict__ qhi,
    const unsigned short* __restrict__ khi,
    const unsigned short* __restrict__ vth,
    const unsigned long long* __restrict__ maskbits,
    float* __restrict__ out)
{
    const int h    = blockIdx.x & 7;    // XCD-affinity remap
    const int qb   = blockIdx.x >> 3;
    const int tid  = threadIdx.x;
    const int wave = tid >> 6;
    const int lane = tid & 63;
    const int l16  = lane & 15;
    const int quad = lane >> 4;

    // LDS union: stream phase = Qh[64][72] + ps[4][64][88]  (54.3 KB)
    //            reduce phase = ored[4][64][64] f32 + lred[4][64] f32 (66.5 KB)
    __shared__ __align__(16) char SM[66560];
    unsigned short* Qh = (unsigned short*)SM;                          // [64][72]
    unsigned short* ps = (unsigned short*)(SM + 9216 + wave*11264);    // [64][88]

    const size_t qbase = ((size_t)(h*64 + qb)) << 12;

    // ---- stage swizzled Q (hi only) to LDS, shared by all waves ----
    for (int c = tid; c < 512; c += 256) {
        int row = c >> 3, cc = c & 7;
        int sw = cc ^ ((row >> 2) & 7);
        uint4 th = *(const uint4*)(qhi + qbase + row*64 + cc*8);
        *(uint4*)&Qh[row*72 + sw*8] = th;
    }

    // ---- my private k-block list: every 4th set bit, starting at rank `wave`
    unsigned long long rem = maskbits[(h << 6) + qb];
    for (int s = 0; s < wave; ++s) rem &= rem - 1;
    int cur = rem ? (int)__builtin_ctzll(rem) : -1;

    // all-ones bf16 B-fragment (1.0 = 0x3F80): rowsum MFMA
    const bf16x8 ones = {0x3F80, 0x3F80, 0x3F80, 0x3F80, 0x3F80, 0x3F80, 0x3F80, 0x3F80};

    f32x4 lacc[4];
    f32x4 oacc[4][4];
    #pragma unroll
    for (int qt = 0; qt < 4; ++qt) {
        lacc[qt] = (f32x4){0.f, 0.f, 0.f, 0.f};
        #pragma unroll
        for (int dt = 0; dt < 4; ++dt) oacc[qt][dt] = (f32x4){0.f, 0.f, 0.f, 0.f};
    }

    bf16x8 kf[4][2], vf[4][2];
    if (cur >= 0) {      // first-tile loads issued before the Q barrier (overlap)
        const size_t tb = ((size_t)(h*64 + cur)) << 12;
        #pragma unroll
        for (int t = 0; t < 4; ++t)
            #pragma unroll
            for (int kc = 0; kc < 2; ++kc) {
                kf[t][kc] = *(const bf16x8*)(khi + tb + (l16*4 + t)*64 + (((kc*4 + quad) ^ (l16 & 7))*8));
                vf[t][kc] = *(const bf16x8*)(vth + tb + (t*16 + l16)*64 + (((kc*4 + quad) ^ (l16 & 7))*8));
            }
    }
    __syncthreads();   // Q published

    while (cur >= 0) {
        rem &= rem - 1; rem &= rem - 1; rem &= rem - 1; rem &= rem - 1;  // pop 4 (0-safe)
        const int nxt = rem ? (int)__builtin_ctzll(rem) : -1;

        // ---- QK + fixed-M softmax, per q-tile (Q = bf16 hi only) ----
        #pragma unroll
        for (int qt = 0; qt < 4; ++qt) {
            const int xb = (qt*4 + (l16 >> 2)) & 7;
            bf16x8 ah[2];
            #pragma unroll
            for (int kc = 0; kc < 2; ++kc) {
                const int off = (qt*16 + l16)*72 + (((kc*4 + quad) ^ xb)*8);
                ah[kc] = *(const bf16x8*)&Qh[off];
            }
            f32x4 sacc[4];
            #pragma unroll
            for (int t = 0; t < 4; ++t) sacc[t] = (f32x4){0.f, 0.f, 0.f, 0.f};
            __builtin_amdgcn_s_setprio(1);
            #pragma unroll
            for (int t = 0; t < 4; ++t)
                #pragma unroll
                for (int kc = 0; kc < 2; ++kc)
                    sacc[t] = __builtin_amdgcn_mfma_f32_16x16x32_bf16(ah[kc], kf[t][kc], sacc[t], 0, 0, 0);
            __builtin_amdgcn_s_setprio(0);
            // p = exp(s*0.125 - 16) = exp2(fma(s, 0.125*log2e, -16*log2e))
            #pragma unroll
            for (int r = 0; r < 4; ++r) {
                float p0 = __builtin_amdgcn_exp2f(fmaf(sacc[0][r], 0.18033688f, -23.083121f));
                float p1 = __builtin_amdgcn_exp2f(fmaf(sacc[1][r], 0.18033688f, -23.083121f));
                float p2 = __builtin_amdgcn_exp2f(fmaf(sacc[2][r], 0.18033688f, -23.083121f));
                float p3 = __builtin_amdgcn_exp2f(fmaf(sacc[3][r], 0.18033688f, -23.083121f));
                __hip_bfloat162 a01 = __float22bfloat162_rn(make_float2(p0, p1));
                __hip_bfloat162 a23 = __float22bfloat162_rn(make_float2(p2, p3));
                uint2 w; w.x = *(unsigned*)&a01; w.y = *(unsigned*)&a23;
                *(uint2*)&ps[(qt*16 + quad*4 + r)*88 + l16*4] = w;
            }
        }
        // ---- prefetch next K (kf regs free after QK) ----
        if (nxt >= 0) {
            const size_t tb = ((size_t)(h*64 + nxt)) << 12;
            #pragma unroll
            for (int t = 0; t < 4; ++t)
                #pragma unroll
                for (int kc = 0; kc < 2; ++kc)
                    kf[t][kc] = *(const bf16x8*)(khi + tb + (l16*4 + t)*64 + (((kc*4 + quad) ^ (l16 & 7))*8));
        }
        // ---- PV + l-rowsum (ones-MFMA), ps wave-local ----
        #pragma unroll
        for (int qt = 0; qt < 4; ++qt) {
            bf16x8 pf0 = *(const bf16x8*)&ps[(qt*16 + l16)*88 + quad*8];
            bf16x8 pf1 = *(const bf16x8*)&ps[(qt*16 + l16)*88 + 32 + quad*8];
            __builtin_amdgcn_s_setprio(1);
            lacc[qt] = __builtin_amdgcn_mfma_f32_16x16x32_bf16(pf0, ones, lacc[qt], 0, 0, 0);
            lacc[qt] = __builtin_amdgcn_mfma_f32_16x16x32_bf16(pf1, ones, lacc[qt], 0, 0, 0);
            #pragma unroll
            for (int dt = 0; dt < 4; ++dt) {
                oacc[qt][dt] = __builtin_amdgcn_mfma_f32_16x16x32_bf16(pf0, vf[dt][0], oacc[qt][dt], 0, 0, 0);
                oacc[qt][dt] = __builtin_amdgcn_mfma_f32_16x16x32_bf16(pf1, vf[dt][1], oacc[qt][dt], 0, 0, 0);
            }
            __builtin_amdgcn_s_setprio(0);
        }
        // ---- prefetch next V (vf regs free after PV) ----
        if (nxt >= 0) {
            const size_t tb = ((size_t)(h*64 + nxt)) << 12;
            #pragma unroll
            for (int dt = 0; dt < 4; ++dt)
                #pragma unroll
                for (int kc = 0; kc < 2; ++kc)
                    vf[dt][kc] = *(const bf16x8*)(vth + tb + (dt*16 + l16)*64 + (((kc*4 + quad) ^ (l16 & 7))*8));
        }
        cur = nxt;
    }

    // ---- cross-wave reduce: O = sum_w O_w / sum_w l_w ----
    // lacc[qt][r] already holds the full rowsum in every lane.
    __syncthreads();   // stream LDS (Q, ps) dead
    float* ored = (float*)SM;            // [4][64][64]
    float* lred = (float*)(SM + 65536);  // [4][64]
    #pragma unroll
    for (int qt = 0; qt < 4; ++qt) {
        #pragma unroll
        for (int dt = 0; dt < 4; ++dt)
            #pragma unroll
            for (int r = 0; r < 4; ++r)
                ored[wave*4096 + (qt*16 + quad*4 + r)*64 + dt*16 + l16] = oacc[qt][dt][r];
        if (l16 == 0) {
            #pragma unroll
            for (int r = 0; r < 4; ++r)
                lred[wave*64 + qt*16 + quad*4 + r] = lacc[qt][r];
        }
    }
    __syncthreads();
    {
        const int row = tid >> 2;
        const int d0  = (tid & 3) << 4;
        float l = lred[row] + lred[64 + row] + lred[128 + row] + lred[192 + row];
        float inv = 1.f / l;
        float* og = out + ((size_t)h*L_ + (size_t)qb*64 + row)*D_ + d0;
        #pragma unroll
        for (int j = 0; j < 16; j += 4) {
            float4 a = *(float4*)&ored[0*4096 + row*64 + d0 + j];
            float4 b = *(float4*)&ored[1*4096 + row*64 + d0 + j];
            float4 c = *(float4*)&ored[2*4096 + row*64 + d0 + j];
            float4 d = *(float4*)&ored[3*4096 + row*64 + d0 + j];
            float4 rr;
            rr.x = (a.x + b.x + c.x + d.x) * inv;
            rr.y = (a.y + b.y + c.y + d.y) * inv;
            rr.z = (a.z + b.z + c.z + d.z) * inv;
            rr.w = (a.w + b.w + c.w + d.w) * inv;
            *(float4*)(og + j) = rr;
        }
    }
}

// ---------------------------------------------------------------------------
// Fallback path (round-6, proven): mask_kernel4 + attn_v3, only if ws small.
// ---------------------------------------------------------------------------
__global__ __launch_bounds__(256, 4) void mask_kernel4(
    const float* __restrict__ q, const float* __restrict__ k,
    const int* __restrict__ sidxq, const int* __restrict__ sidxk,
    unsigned long long* __restrict__ maskbits)
{
    const int h   = blockIdx.x >> 6;
    const int qb  = blockIdx.x & 63;
    const int tid = threadIdx.x;
    const int rg  = tid >> 5;
    const int cg  = tid & 31;

    __shared__ float sq[16][68];
    __shared__ float skc[128][68];
    __shared__ float E[16][64];
    __shared__ float Z[16];
    __shared__ float pooled[64];
    __shared__ int iq[16], ik[16];

    if (tid < 16) { iq[tid] = sidxq[h*16 + tid]; ik[tid] = sidxk[h*16 + tid]; }
    for (int e = tid; e < 16*64; e += 256) (&E[0][0])[e] = 0.f;
    __syncthreads();
    {
        int j = tid >> 4, d4 = tid & 15;
        int grow = h*L_ + qb*64 + iq[j];
        *(float4*)&sq[j][d4*4] = *(const float4*)(q + (size_t)grow*D_ + d4*4);
    }
    for (int cc = 0; cc < 8; ++cc) {
        for (int i = tid; i < 2048; i += 256) {
            int col = i >> 4, d4 = i & 15;
            int colg = cc*128 + col;
            int grow = h*L_ + (colg >> 4)*64 + ik[colg & 15];
            *(float4*)&skc[col][d4*4] = *(const float4*)(k + (size_t)grow*D_ + d4*4);
        }
        __syncthreads();
        float acc[2][4] = {{0.f,0.f,0.f,0.f},{0.f,0.f,0.f,0.f}};
        #pragma unroll 4
        for (int d4 = 0; d4 < 16; ++d4) {
            float4 qv0 = *(const float4*)&sq[rg*2 + 0][d4*4];
            float4 qv1 = *(const float4*)&sq[rg*2 + 1][d4*4];
            #pragma unroll
            for (int j = 0; j < 4; ++j) {
                float4 kv = *(const float4*)&skc[cg + 32*j][d4*4];
                acc[0][j] += qv0.x*kv.x + qv0.y*kv.y + qv0.z*kv.z + qv0.w*kv.w;
                acc[1][j] += qv1.x*kv.x + qv1.y*kv.y + qv1.z*kv.z + qv1.w*kv.w;
            }
        }
        #pragma unroll
        for (int j = 0; j < 4; ++j) {
            int kb = cc*8 + (cg >> 4) + 2*j;
            #pragma unroll
            for (int i = 0; i < 2; ++i) {
                float p = __expf(acc[i][j] * 0.125f);
                p += __shfl_xor(p, 1);
                p += __shfl_xor(p, 2);
                p += __shfl_xor(p, 4);
                p += __shfl_xor(p, 8);
                if ((cg & 15) == 0) E[rg*2 + i][kb] += p;
            }
        }
        __syncthreads();
    }
    if (tid < 16) {
        float s = 0.f;
        #pragma unroll
        for (int kb = 0; kb < 64; ++kb) s += E[tid][kb];
        Z[tid] = s;
    }
    __syncthreads();
    if (tid < 64) {
        float s = 0.f;
        #pragma unroll
        for (int t = 0; t < 16; ++t) s += E[t][tid] / Z[t];
        pooled[tid] = s;
    }
    __syncthreads();
    if (tid < 64) {
        float pi = pooled[tid];
        float tot = 0.f, bef = 0.f;
        for (int j2 = 0; j2 < 64; ++j2) {
            float pj = pooled[j2];
            tot += pj;
            if (pj > pi || (pj == pi && j2 < tid)) bef += pj;
        }
        bool att = (bef / tot) < 0.5f;
        unsigned long long bits = __ballot(att);
        if (tid == 0) maskbits[h*64 + qb] = bits;
    }
}

__global__ __launch_bounds__(256, 3) void attn_v3(
    const float* __restrict__ q, const float* __restrict__ k, const float* __restrict__ v,
    const unsigned long long* __restrict__ maskbits, float* __restrict__ out)
{
    const int h = blockIdx.x >> 6, qb = blockIdx.x & 63;
    const int tid = threadIdx.x, wave = tid >> 6, lane = tid & 63;
    const int l16 = lane & 15, quad = lane >> 4;
    __shared__ __align__(16) unsigned short ks_hi[64][72];
    __shared__ __align__(16) unsigned short ks_lo[64][72];
    __shared__ __align__(16) unsigned short vt_hi[64][72];
    __shared__ __align__(16) unsigned short vt_lo[64][72];
    __shared__ __align__(16) unsigned short ps[4][16][72];

    const float4* qg = (const float4*)(q + ((size_t)h*L_ + (size_t)qb*64)*D_);
    for (int i4 = tid; i4 < 1024; i4 += 256) {
        float4 t = qg[i4];
        int r = i4 >> 4, c = (i4 & 15) << 2;
        ushort4 hi, lo;
        hi.x = f2bf(t.x); lo.x = f2bf(t.x - bf2f(hi.x));
        hi.y = f2bf(t.y); lo.y = f2bf(t.y - bf2f(hi.y));
        hi.z = f2bf(t.z); lo.z = f2bf(t.z - bf2f(hi.z));
        hi.w = f2bf(t.w); lo.w = f2bf(t.w - bf2f(hi.w));
        *(ushort4*)&ks_hi[r][c] = hi;
        *(ushort4*)&ks_lo[r][c] = lo;
    }
    const unsigned long long bm = maskbits[(h << 6) + qb];
    __syncthreads();
    bf16x8 qhi2[2], qlo2[2];
    #pragma unroll
    for (int kc = 0; kc < 2; ++kc) {
        qhi2[kc] = *(const bf16x8*)&ks_hi[wave*16 + l16][kc*32 + quad*8];
        qlo2[kc] = *(const bf16x8*)&ks_lo[wave*16 + l16][kc*32 + quad*8];
    }
    __syncthreads();
    float m_i[4], l_i[4];
    f32x4 oacc[4];
    #pragma unroll
    for (int r = 0; r < 4; ++r) { m_i[r] = -1e30f; l_i[r] = 0.f; }
    #pragma unroll
    for (int t = 0; t < 4; ++t) oacc[t] = (f32x4){0.f, 0.f, 0.f, 0.f};
    for (int kb = 0; kb < 64; ++kb) {
        if (!((bm >> kb) & 1ull)) continue;
        const float4* kg = (const float4*)(k + ((size_t)h*L_ + (size_t)kb*64)*D_);
        const float*  vg = v + ((size_t)h*L_ + (size_t)kb*64)*D_;
        for (int i4 = tid; i4 < 1024; i4 += 256) {
            float4 t = kg[i4];
            int r = i4 >> 4, c = (i4 & 15) << 2;
            ushort4 hi, lo;
            hi.x = f2bf(t.x); lo.x = f2bf(t.x - bf2f(hi.x));
            hi.y = f2bf(t.y); lo.y = f2bf(t.y - bf2f(hi.y));
            hi.z = f2bf(t.z); lo.z = f2bf(t.z - bf2f(hi.z));
            hi.w = f2bf(t.w); lo.w = f2bf(t.w - bf2f(hi.w));
            *(ushort4*)&ks_hi[r][c] = hi;
            *(ushort4*)&ks_lo[r][c] = lo;
        }
        for (int tsk = tid; tsk < 512; tsk += 256) {
            int rp = tsk >> 4;
            int c  = (tsk & 15) << 2;
            float4 a0 = *(const float4*)(vg + (size_t)(2*rp)*D_ + c);
            float4 a1 = *(const float4*)(vg + (size_t)(2*rp+1)*D_ + c);
            #pragma unroll
            for (int j = 0; j < 4; ++j) {
                float x0 = (j==0)?a0.x:(j==1)?a0.y:(j==2)?a0.z:a0.w;
                float x1 = (j==0)?a1.x:(j==1)?a1.y:(j==2)?a1.z:a1.w;
                unsigned short h0 = f2bf(x0), h1b = f2bf(x1);
                *(unsigned*)&vt_hi[c+j][2*rp] = (unsigned)h0 | ((unsigned)h1b << 16);
                unsigned short lo0 = f2bf(x0 - bf2f(h0)), lo1 = f2bf(x1 - bf2f(h1b));
                *(unsigned*)&vt_lo[c+j][2*rp] = (unsigned)lo0 | ((unsigned)lo1 << 16);
            }
        }
        __syncthreads();
        f32x4 sacc[4];
        #pragma unroll
        for (int t = 0; t < 4; ++t) sacc[t] = (f32x4){0.f, 0.f, 0.f, 0.f};
        #pragma unroll
        for (int t = 0; t < 4; ++t) {
            #pragma unroll
            for (int kc = 0; kc < 2; ++kc) {
                bf16x8 khi2 = *(const bf16x8*)&ks_hi[t*16 + l16][kc*32 + quad*8];
                bf16x8 klo2 = *(const bf16x8*)&ks_lo[t*16 + l16][kc*32 + quad*8];
                sacc[t] = __builtin_amdgcn_mfma_f32_16x16x32_bf16(qhi2[kc], khi2, sacc[t], 0, 0, 0);
                sacc[t] = __builtin_amdgcn_mfma_f32_16x16x32_bf16(qhi2[kc], klo2, sacc[t], 0, 0, 0);
                sacc[t] = __builtin_amdgcn_mfma_f32_16x16x32_bf16(qlo2[kc], khi2, sacc[t], 0, 0, 0);
            }
        }
        #pragma unroll
        for (int t = 0; t < 4; ++t) sacc[t] *= 0.125f;
        float rowmax[4];
        #pragma unroll
        for (int r = 0; r < 4; ++r)
            rowmax[r] = fmaxf(fmaxf(sacc[0][r], sacc[1][r]), fmaxf(sacc[2][r], sacc[3][r]));
        #pragma unroll
        for (int off = 1; off < 16; off <<= 1)
            #pragma unroll
            for (int r = 0; r < 4; ++r)
                rowmax[r] = fmaxf(rowmax[r], __shfl_xor(rowmax[r], off));
        float al[4], rs[4];
        #pragma unroll
        for (int r = 0; r < 4; ++r) {
            float mnew = fmaxf(m_i[r], rowmax[r]);
            al[r] = __expf(m_i[r] - mnew);
            m_i[r] = mnew;
            float acc = 0.f;
            #pragma unroll
            for (int t = 0; t < 4; ++t) {
                float p = __expf(sacc[t][r] - mnew);
                unsigned short pb = f2bf(p);
                ps[wave][quad*4 + r][t*16 + l16] = pb;
                acc += bf2f(pb);
            }
            rs[r] = acc;
        }
        #pragma unroll
        for (int off = 1; off < 16; off <<= 1)
            #pragma unroll
            for (int r = 0; r < 4; ++r)
                rs[r] += __shfl_xor(rs[r], off);
        #pragma unroll
        for (int r = 0; r < 4; ++r) l_i[r] = l_i[r] * al[r] + rs[r];
        #pragma unroll
        for (int t = 0; t < 4; ++t)
            #pragma unroll
            for (int r = 0; r < 4; ++r) oacc[t][r] *= al[r];
        bf16x8 pf[2];
        #pragma unroll
        for (int kc = 0; kc < 2; ++kc)
            pf[kc] = *(const bf16x8*)&ps[wave][l16][kc*32 + quad*8];
        #pragma unroll
        for (int t = 0; t < 4; ++t) {
            #pragma unroll
            for (int kc = 0; kc < 2; ++kc) {
                bf16x8 vhif = *(const bf16x8*)&vt_hi[t*16 + l16][kc*32 + quad*8];
                bf16x8 vlof = *(const bf16x8*)&vt_lo[t*16 + l16][kc*32 + quad*8];
                oacc[t] = __builtin_amdgcn_mfma_f32_16x16x32_bf16(pf[kc], vhif, oacc[t], 0, 0, 0);
                oacc[t] = __builtin_amdgcn_mfma_f32_16x16x32_bf16(pf[kc], vlof, oacc[t], 0, 0, 0);
            }
        }
        __syncthreads();
    }
    float* og = out + ((size_t)h*L_ + (size_t)qb*64)*D_ + (size_t)(wave*16 + quad*4)*D_;
    #pragma unroll
    for (int r = 0; r < 4; ++r) {
        float inv = 1.f / l_i[r];
        #pragma unroll
        for (int t = 0; t < 4; ++t)
            og[(size_t)r*D_ + t*16 + l16] = oacc[t][r] * inv;
    }
}

extern "C" void kernel_launch(void* const* d_in, const int* in_sizes, int n_in,
                              void* d_out, int out_size, void* d_ws, size_t ws_size,
                              hipStream_t stream) {
    const float* q = (const float*)d_in[0];
    const float* k = (const float*)d_in[1];
    const float* v = (const float*)d_in[2];
    const int* siq = (const int*)d_in[3];
    const int* sik = (const int*)d_in[4];
    float* out = (float*)d_out;

    char* ws = (char*)d_ws;
    unsigned long long* mask = (unsigned long long*)ws;          // 4 KB
    const size_t TEN = (size_t)H_*L_*D_;                         // 2,097,152 elems
    const size_t SKN = (size_t)H_*1024*64;                       //   524,288 elems
    unsigned short* qhi = (unsigned short*)(ws + 4096);
    unsigned short* qlo = qhi + TEN;
    unsigned short* khi = qlo + TEN;
    unsigned short* vth = khi + TEN;
    unsigned short* skh = vth + TEN;
    unsigned short* skl = skh + SKN;
    const size_t need = 4096 + (4*TEN + 2*SKN)*sizeof(unsigned short);  // ~18.9 MB

    if (ws_size >= need) {
        prep_kernel<<<dim3(H_*NB_), dim3(256), 0, stream>>>(q, k, v, sik, qhi, qlo, khi, vth, skh, skl);
        mask_mfma<<<dim3(H_*NB_), dim3(256), 0, stream>>>(qhi, qlo, skh, skl, siq, mask);
        attn_wave<<<dim3(H_*NB_), dim3(256), 0, stream>>>(qhi, khi, vth, mask, out);
    } else {
        mask_kernel4<<<dim3(H_*NB_), dim3(256), 0, stream>>>(q, k, siq, sik, mask);
        attn_v3<<<dim3(H_*NB_), dim3(256), 0, stream>>>(q, k, v, mask, out);
    }
}

// Round 11
// 129.730 us; speedup vs baseline: 1.0647x; 1.0382x over previous
//
#include <hip/hip_runtime.h>
#include <hip/hip_bf16.h>

// B=1, H=8, L=4096, D=64; 64x64 blocks; 16 samples/block. Inputs f32, output f32.
#define H_ 8
#define L_ 4096
#define D_ 64
#define NB_ 64

typedef __attribute__((ext_vector_type(8))) short bf16x8;
typedef __attribute__((ext_vector_type(4))) float f32x4;

__device__ __forceinline__ unsigned short f2bf(float x) {   // RNE f32->bf16
    unsigned u = __float_as_uint(x);
    u += 0x7fff + ((u >> 16) & 1);
    return (unsigned short)(u >> 16);
}
__device__ __forceinline__ float bf2f(unsigned short s) {
    return __uint_as_float(((unsigned)s) << 16);
}

// ---------------------------------------------------------------------------
// Preprocess (unchanged — qlo still produced for the fused mask phase).
// ---------------------------------------------------------------------------
__global__ __launch_bounds__(256) void prep_kernel(
    const float* __restrict__ q, const float* __restrict__ k, const float* __restrict__ v,
    const int* __restrict__ sidxk,
    unsigned short* __restrict__ qhi, unsigned short* __restrict__ qlo,
    unsigned short* __restrict__ khi,
    unsigned short* __restrict__ vth,
    unsigned short* __restrict__ skh, unsigned short* __restrict__ skl)
{
    const int h  = blockIdx.x >> 6;
    const int tb = blockIdx.x & 63;
    const int tid = threadIdx.x;
    __shared__ float vst[64][68];

    const size_t te = ((size_t)(h*64 + tb)) << 12;   // tile base (elements)
    const float4* qg = (const float4*)(q + te);
    for (int i4 = tid; i4 < 1024; i4 += 256) {
        float4 t = qg[i4];
        ushort4 hi, lo;
        hi.x = f2bf(t.x); lo.x = f2bf(t.x - bf2f(hi.x));
        hi.y = f2bf(t.y); lo.y = f2bf(t.y - bf2f(hi.y));
        hi.z = f2bf(t.z); lo.z = f2bf(t.z - bf2f(hi.z));
        hi.w = f2bf(t.w); lo.w = f2bf(t.w - bf2f(hi.w));
        *(ushort4*)(qhi + te + i4*4) = hi;
        *(ushort4*)(qlo + te + i4*4) = lo;
    }
    const float4* kg = (const float4*)(k + te);
    for (int i4 = tid; i4 < 1024; i4 += 256) {
        float4 t = kg[i4];
        int r = i4 >> 4, c4 = i4 & 15;
        int sch = (c4 >> 1) ^ ((r >> 2) & 7);   // matches attn's permuted-key S tiles
        ushort4 hi;
        hi.x = f2bf(t.x); hi.y = f2bf(t.y); hi.z = f2bf(t.z); hi.w = f2bf(t.w);
        *(ushort4*)(khi + te + r*64 + sch*8 + (c4 & 1)*4) = hi;
    }
    // sampled-K rows for the MFMA mask
    {
        int t = tid >> 4, d4 = tid & 15;
        int srow = tb*64 + sidxk[h*16 + t];
        float4 x = *(const float4*)(k + ((size_t)h*L_ + srow)*D_ + d4*4);
        ushort4 hi, lo;
        hi.x = f2bf(x.x); lo.x = f2bf(x.x - bf2f(hi.x));
        hi.y = f2bf(x.y); lo.y = f2bf(x.y - bf2f(hi.y));
        hi.z = f2bf(x.z); lo.z = f2bf(x.z - bf2f(hi.z));
        hi.w = f2bf(x.w); lo.w = f2bf(x.w - bf2f(hi.w));
        int sch = (d4 >> 1) ^ (t & 7);
        size_t dst = ((size_t)h*1024 + tb*16 + t)*64 + sch*8 + (d4 & 1)*4;
        *(ushort4*)(skh + dst) = hi;
        *(ushort4*)(skl + dst) = lo;
    }
    const float4* vg = (const float4*)(v + te);
    for (int i4 = tid; i4 < 1024; i4 += 256) {
        float4 t = vg[i4];
        *(float4*)&vst[i4 >> 4][(i4 & 15)*4] = t;
    }
    __syncthreads();
    for (int u = tid; u < 512; u += 256) {
        int d = u >> 3, kc8 = u & 7;
        int sch = kc8 ^ (d & 7);
        ushort4 h0, h1;
        h0.x = f2bf(vst[kc8*8+0][d]); h0.y = f2bf(vst[kc8*8+1][d]);
        h0.z = f2bf(vst[kc8*8+2][d]); h0.w = f2bf(vst[kc8*8+3][d]);
        h1.x = f2bf(vst[kc8*8+4][d]); h1.y = f2bf(vst[kc8*8+5][d]);
        h1.z = f2bf(vst[kc8*8+6][d]); h1.w = f2bf(vst[kc8*8+7][d]);
        *(ushort4*)(vth + te + d*64 + sch*8 + 0) = h0;
        *(ushort4*)(vth + te + d*64 + sch*8 + 4) = h1;
    }
}

// ---------------------------------------------------------------------------
// Kernel B (v16): FUSED mask + wave-private attention.
// ROUND 21. R10: setprio neutral (134.7 vs R7's 133.4, inside fill noise);
// source-level levers on the attn loop are exhausted (work ladder done,
// chain variants +-3, TLP null x3, setprio ~0). Last mechanical lever:
// mask_mfma and attn_wave have IDENTICAL grid mappings (block=(h,qb), same
// XCD remap) and communicate through one 8-byte maskbits value -> fuse:
//  - removes one launch boundary (~2us gap + straggler tail),
//  - block i's attn phase overlaps block j's mask phase on the same CU
//    (different phases fill each other's stalls),
//  - bits stay in LDS (no global round-trip).
// Mask phase LDS (ch/cl/E/Z/pooled ~37KB) unions under the attn 66.5KB
// buffer; one barrier at the phase boundary publishes bits after all
// mask-LDS reads. attn body = R7's best-measured v13 (no setprio).
// ---------------------------------------------------------------------------
__global__ __launch_bounds__(256, 2) void mask_attn(
    const unsigned short* __restrict__ qhi, const unsigned short* __restrict__ qlo,
    const unsigned short* __restrict__ khi,
    const unsigned short* __restrict__ vth,
    const unsigned short* __restrict__ skh, const unsigned short* __restrict__ skl,
    const int* __restrict__ sidxq,
    float* __restrict__ out)
{
    const int h    = blockIdx.x & 7;    // XCD-affinity remap
    const int qb   = blockIdx.x >> 3;
    const int tid  = threadIdx.x;
    const int wave = tid >> 6;
    const int lane = tid & 63;
    const int l16  = lane & 15;
    const int quad = lane >> 4;

    // LDS union:
    //  mask phase : ch[8192]u16 (16K) + cl[8192]u16 (16K) + E[16][64]f32 (4K)
    //               + Z[16]f32 + pooled[64]f32                     (~37.2 KB)
    //  attn stream: Qh[64][72]u16 (9216B) + ps[4][64][88]u16       (54.3 KB)
    //  reduce     : ored[4][64][64]f32 (64K) + lred[4][64]f32 (1K) (66.5 KB)
    __shared__ __align__(16) char SM[66560];
    __shared__ unsigned long long bmShared;

    const size_t qbase = (((size_t)(h*64 + qb)) << 12);

    // ======================= PHASE 1: block mask =======================
    {
        unsigned short* ch = (unsigned short*)SM;            // 16384 B
        unsigned short* cl = (unsigned short*)(SM + 16384);  // 16384 B
        float* E  = (float*)(SM + 32768);                    // [16][64]
        float* Zz = (float*)(SM + 36864);                    // [16]
        float* pooled = (float*)(SM + 36928);                // [64]

        for (int e = tid; e < 16*64; e += 256) E[e] = 0.f;

        const int iqr = sidxq[h*16 + l16];
        const size_t qo = qbase + (size_t)iqr*64;
        bf16x8 qh[2], ql[2];
        qh[0] = *(const bf16x8*)(qhi + qo + quad*8);
        qh[1] = *(const bf16x8*)(qhi + qo + 32 + quad*8);
        ql[0] = *(const bf16x8*)(qlo + qo + quad*8);
        ql[1] = *(const bf16x8*)(qlo + qo + 32 + quad*8);
        __syncthreads();

        for (int cc = 0; cc < 8; ++cc) {
            const bf16x8* gh = (const bf16x8*)(skh + ((size_t)h*1024 + cc*128)*64);
            const bf16x8* gl = (const bf16x8*)(skl + ((size_t)h*1024 + cc*128)*64);
            for (int i = tid; i < 1024; i += 256) {
                ((bf16x8*)ch)[i] = gh[i];
                ((bf16x8*)cl)[i] = gl[i];
            }
            __syncthreads();

            #pragma unroll
            for (int tt = 0; tt < 2; ++tt) {
                const int kb = cc*8 + wave*2 + tt;
                const int nb = (wave*2 + tt)*16;
                f32x4 sacc = (f32x4){0.f, 0.f, 0.f, 0.f};
                #pragma unroll
                for (int kc = 0; kc < 2; ++kc) {
                    const int off = (nb + l16)*64 + (((kc*4 + quad) ^ (l16 & 7))*8);
                    bf16x8 kh = *(const bf16x8*)&ch[off];
                    bf16x8 kl = *(const bf16x8*)&cl[off];
                    sacc = __builtin_amdgcn_mfma_f32_16x16x32_bf16(qh[kc], kh, sacc, 0, 0, 0);
                    sacc = __builtin_amdgcn_mfma_f32_16x16x32_bf16(qh[kc], kl, sacc, 0, 0, 0);
                    sacc = __builtin_amdgcn_mfma_f32_16x16x32_bf16(ql[kc], kh, sacc, 0, 0, 0);
                    sacc = __builtin_amdgcn_mfma_f32_16x16x32_bf16(ql[kc], kl, sacc, 0, 0, 0);
                }
                #pragma unroll
                for (int r = 0; r < 4; ++r) {
                    float p = __expf(sacc[r] * 0.125f);
                    p += __shfl_xor(p, 1);
                    p += __shfl_xor(p, 2);
                    p += __shfl_xor(p, 4);
                    p += __shfl_xor(p, 8);
                    if (l16 == 0) E[(quad*4 + r)*64 + kb] = p;
                }
            }
            __syncthreads();
        }

        if (tid < 16) {
            float s = 0.f;
            #pragma unroll
            for (int kb = 0; kb < 64; ++kb) s += E[tid*64 + kb];
            Zz[tid] = s;
        }
        __syncthreads();
        if (tid < 64) {
            float s = 0.f;
            #pragma unroll
            for (int t = 0; t < 16; ++t) s += E[t*64 + tid] / Zz[t];
            pooled[tid] = s;
        }
        __syncthreads();
        if (tid < 64) {
            float pi = pooled[tid];
            float tot = 0.f, bef = 0.f;
            for (int j2 = 0; j2 < 64; ++j2) {
                float pj = pooled[j2];
                tot += pj;
                if (pj > pi || (pj == pi && j2 < tid)) bef += pj;
            }
            bool att = (bef / tot) < 0.5f;
            unsigned long long bits = __ballot(att);
            if (tid == 0) bmShared = bits;
        }
        __syncthreads();   // publishes bmShared; all mask-LDS reads complete
    }
    const unsigned long long bm = bmShared;

    // ======================= PHASE 2: attention ========================
    unsigned short* Qh = (unsigned short*)SM;                          // [64][72]
    unsigned short* ps = (unsigned short*)(SM + 9216 + wave*11264);    // [64][88]

    // ---- stage swizzled Q (hi only) to LDS, shared by all waves ----
    for (int c = tid; c < 512; c += 256) {
        int row = c >> 3, cc = c & 7;
        int sw = cc ^ ((row >> 2) & 7);
        uint4 th = *(const uint4*)(qhi + qbase + row*64 + cc*8);
        *(uint4*)&Qh[row*72 + sw*8] = th;
    }

    // ---- my private k-block list: every 4th set bit, starting at rank `wave`
    unsigned long long rem = bm;
    for (int s = 0; s < wave; ++s) rem &= rem - 1;
    int cur = rem ? (int)__builtin_ctzll(rem) : -1;

    // all-ones bf16 B-fragment (1.0 = 0x3F80): rowsum MFMA
    const bf16x8 ones = {0x3F80, 0x3F80, 0x3F80, 0x3F80, 0x3F80, 0x3F80, 0x3F80, 0x3F80};

    f32x4 lacc[4];
    f32x4 oacc[4][4];
    #pragma unroll
    for (int qt = 0; qt < 4; ++qt) {
        lacc[qt] = (f32x4){0.f, 0.f, 0.f, 0.f};
        #pragma unroll
        for (int dt = 0; dt < 4; ++dt) oacc[qt][dt] = (f32x4){0.f, 0.f, 0.f, 0.f};
    }

    bf16x8 kf[4][2], vf[4][2];
    if (cur >= 0) {      // first-tile loads issued before the Q barrier (overlap)
        const size_t tb = ((size_t)(h*64 + cur)) << 12;
        #pragma unroll
        for (int t = 0; t < 4; ++t)
            #pragma unroll
            for (int kc = 0; kc < 2; ++kc) {
                kf[t][kc] = *(const bf16x8*)(khi + tb + (l16*4 + t)*64 + (((kc*4 + quad) ^ (l16 & 7))*8));
                vf[t][kc] = *(const bf16x8*)(vth + tb + (t*16 + l16)*64 + (((kc*4 + quad) ^ (l16 & 7))*8));
            }
    }
    __syncthreads();   // Q published

    while (cur >= 0) {
        rem &= rem - 1; rem &= rem - 1; rem &= rem - 1; rem &= rem - 1;  // pop 4 (0-safe)
        const int nxt = rem ? (int)__builtin_ctzll(rem) : -1;

        // ---- QK + fixed-M softmax, per q-tile (Q = bf16 hi only) ----
        #pragma unroll
        for (int qt = 0; qt < 4; ++qt) {
            const int xb = (qt*4 + (l16 >> 2)) & 7;
            bf16x8 ah[2];
            #pragma unroll
            for (int kc = 0; kc < 2; ++kc) {
                const int off = (qt*16 + l16)*72 + (((kc*4 + quad) ^ xb)*8);
                ah[kc] = *(const bf16x8*)&Qh[off];
            }
            f32x4 sacc[4];
            #pragma unroll
            for (int t = 0; t < 4; ++t) sacc[t] = (f32x4){0.f, 0.f, 0.f, 0.f};
            #pragma unroll
            for (int t = 0; t < 4; ++t)
                #pragma unroll
                for (int kc = 0; kc < 2; ++kc)
                    sacc[t] = __builtin_amdgcn_mfma_f32_16x16x32_bf16(ah[kc], kf[t][kc], sacc[t], 0, 0, 0);
            // p = exp(s*0.125 - 16) = exp2(fma(s, 0.125*log2e, -16*log2e))
            #pragma unroll
            for (int r = 0; r < 4; ++r) {
                float p0 = __builtin_amdgcn_exp2f(fmaf(sacc[0][r], 0.18033688f, -23.083121f));
                float p1 = __builtin_amdgcn_exp2f(fmaf(sacc[1][r], 0.18033688f, -23.083121f));
                float p2 = __builtin_amdgcn_exp2f(fmaf(sacc[2][r], 0.18033688f, -23.083121f));
                float p3 = __builtin_amdgcn_exp2f(fmaf(sacc[3][r], 0.18033688f, -23.083121f));
                __hip_bfloat162 a01 = __float22bfloat162_rn(make_float2(p0, p1));
                __hip_bfloat162 a23 = __float22bfloat162_rn(make_float2(p2, p3));
                uint2 w; w.x = *(unsigned*)&a01; w.y = *(unsigned*)&a23;
                *(uint2*)&ps[(qt*16 + quad*4 + r)*88 + l16*4] = w;
            }
        }
        // ---- prefetch next K (kf regs free after QK) ----
        if (nxt >= 0) {
            const size_t tb = ((size_t)(h*64 + nxt)) << 12;
            #pragma unroll
            for (int t = 0; t < 4; ++t)
                #pragma unroll
                for (int kc = 0; kc < 2; ++kc)
                    kf[t][kc] = *(const bf16x8*)(khi + tb + (l16*4 + t)*64 + (((kc*4 + quad) ^ (l16 & 7))*8));
        }
        // ---- PV + l-rowsum (ones-MFMA), ps wave-local ----
        #pragma unroll
        for (int qt = 0; qt < 4; ++qt) {
            bf16x8 pf0 = *(const bf16x8*)&ps[(qt*16 + l16)*88 + quad*8];
            bf16x8 pf1 = *(const bf16x8*)&ps[(qt*16 + l16)*88 + 32 + quad*8];
            lacc[qt] = __builtin_amdgcn_mfma_f32_16x16x32_bf16(pf0, ones, lacc[qt], 0, 0, 0);
            lacc[qt] = __builtin_amdgcn_mfma_f32_16x16x32_bf16(pf1, ones, lacc[qt], 0, 0, 0);
            #pragma unroll
            for (int dt = 0; dt < 4; ++dt) {
                oacc[qt][dt] = __builtin_amdgcn_mfma_f32_16x16x32_bf16(pf0, vf[dt][0], oacc[qt][dt], 0, 0, 0);
                oacc[qt][dt] = __builtin_amdgcn_mfma_f32_16x16x32_bf16(pf1, vf[dt][1], oacc[qt][dt], 0, 0, 0);
            }
        }
        // ---- prefetch next V (vf regs free after PV) ----
        if (nxt >= 0) {
            const size_t tb = ((size_t)(h*64 + nxt)) << 12;
            #pragma unroll
            for (int dt = 0; dt < 4; ++dt)
                #pragma unroll
                for (int kc = 0; kc < 2; ++kc)
                    vf[dt][kc] = *(const bf16x8*)(vth + tb + (dt*16 + l16)*64 + (((kc*4 + quad) ^ (l16 & 7))*8));
        }
        cur = nxt;
    }

    // ---- cross-wave reduce: O = sum_w O_w / sum_w l_w ----
    // lacc[qt][r] already holds the full rowsum in every lane.
    __syncthreads();   // stream LDS (Q, ps) dead
    float* ored = (float*)SM;            // [4][64][64]
    float* lred = (float*)(SM + 65536);  // [4][64]
    #pragma unroll
    for (int qt = 0; qt < 4; ++qt) {
        #pragma unroll
        for (int dt = 0; dt < 4; ++dt)
            #pragma unroll
            for (int r = 0; r < 4; ++r)
                ored[wave*4096 + (qt*16 + quad*4 + r)*64 + dt*16 + l16] = oacc[qt][dt][r];
        if (l16 == 0) {
            #pragma unroll
            for (int r = 0; r < 4; ++r)
                lred[wave*64 + qt*16 + quad*4 + r] = lacc[qt][r];
        }
    }
    __syncthreads();
    {
        const int row = tid >> 2;
        const int d0  = (tid & 3) << 4;
        float l = lred[row] + lred[64 + row] + lred[128 + row] + lred[192 + row];
        float inv = 1.f / l;
        float* og = out + ((size_t)h*L_ + (size_t)qb*64 + row)*D_ + d0;
        #pragma unroll
        for (int j = 0; j < 16; j += 4) {
            float4 a = *(float4*)&ored[0*4096 + row*64 + d0 + j];
            float4 b = *(float4*)&ored[1*4096 + row*64 + d0 + j];
            float4 c = *(float4*)&ored[2*4096 + row*64 + d0 + j];
            float4 d = *(float4*)&ored[3*4096 + row*64 + d0 + j];
            float4 rr;
            rr.x = (a.x + b.x + c.x + d.x) * inv;
            rr.y = (a.y + b.y + c.y + d.y) * inv;
            rr.z = (a.z + b.z + c.z + d.z) * inv;
            rr.w = (a.w + b.w + c.w + d.w) * inv;
            *(float4*)(og + j) = rr;
        }
    }
}

// ---------------------------------------------------------------------------
// Fallback path (round-6, proven): mask_kernel4 + attn_v3, only if ws small.
// ---------------------------------------------------------------------------
__global__ __launch_bounds__(256, 4) void mask_kernel4(
    const float* __restrict__ q, const float* __restrict__ k,
    const int* __restrict__ sidxq, const int* __restrict__ sidxk,
    unsigned long long* __restrict__ maskbits)
{
    const int h   = blockIdx.x >> 6;
    const int qb  = blockIdx.x & 63;
    const int tid = threadIdx.x;
    const int rg  = tid >> 5;
    const int cg  = tid & 31;

    __shared__ float sq[16][68];
    __shared__ float skc[128][68];
    __shared__ float E[16][64];
    __shared__ float Z[16];
    __shared__ float pooled[64];
    __shared__ int iq[16], ik[16];

    if (tid < 16) { iq[tid] = sidxq[h*16 + tid]; ik[tid] = sidxk[h*16 + tid]; }
    for (int e = tid; e < 16*64; e += 256) (&E[0][0])[e] = 0.f;
    __syncthreads();
    {
        int j = tid >> 4, d4 = tid & 15;
        int grow = h*L_ + qb*64 + iq[j];
        *(float4*)&sq[j][d4*4] = *(const float4*)(q + (size_t)grow*D_ + d4*4);
    }
    for (int cc = 0; cc < 8; ++cc) {
        for (int i = tid; i < 2048; i += 256) {
            int col = i >> 4, d4 = i & 15;
            int colg = cc*128 + col;
            int grow = h*L_ + (colg >> 4)*64 + ik[colg & 15];
            *(float4*)&skc[col][d4*4] = *(const float4*)(k + (size_t)grow*D_ + d4*4);
        }
        __syncthreads();
        float acc[2][4] = {{0.f,0.f,0.f,0.f},{0.f,0.f,0.f,0.f}};
        #pragma unroll 4
        for (int d4 = 0; d4 < 16; ++d4) {
            float4 qv0 = *(const float4*)&sq[rg*2 + 0][d4*4];
            float4 qv1 = *(const float4*)&sq[rg*2 + 1][d4*4];
            #pragma unroll
            for (int j = 0; j < 4; ++j) {
                float4 kv = *(const float4*)&skc[cg + 32*j][d4*4];
                acc[0][j] += qv0.x*kv.x + qv0.y*kv.y + qv0.z*kv.z + qv0.w*kv.w;
                acc[1][j] += qv1.x*kv.x + qv1.y*kv.y + qv1.z*kv.z + qv1.w*kv.w;
            }
        }
        #pragma unroll
        for (int j = 0; j < 4; ++j) {
            int kb = cc*8 + (cg >> 4) + 2*j;
            #pragma unroll
            for (int i = 0; i < 2; ++i) {
                float p = __expf(acc[i][j] * 0.125f);
                p += __shfl_xor(p, 1);
                p += __shfl_xor(p, 2);
                p += __shfl_xor(p, 4);
                p += __shfl_xor(p, 8);
                if ((cg & 15) == 0) E[rg*2 + i][kb] += p;
            }
        }
        __syncthreads();
    }
    if (tid < 16) {
        float s = 0.f;
        #pragma unroll
        for (int kb = 0; kb < 64; ++kb) s += E[tid][kb];
        Z[tid] = s;
    }
    __syncthreads();
    if (tid < 64) {
        float s = 0.f;
        #pragma unroll
        for (int t = 0; t < 16; ++t) s += E[t][tid] / Z[t];
        pooled[tid] = s;
    }
    __syncthreads();
    if (tid < 64) {
        float pi = pooled[tid];
        float tot = 0.f, bef = 0.f;
        for (int j2 = 0; j2 < 64; ++j2) {
            float pj = pooled[j2];
            tot += pj;
            if (pj > pi || (pj == pi && j2 < tid)) bef += pj;
        }
        bool att = (bef / tot) < 0.5f;
        unsigned long long bits = __ballot(att);
        if (tid == 0) maskbits[h*64 + qb] = bits;
    }
}

__global__ __launch_bounds__(256, 3) void attn_v3(
    const float* __restrict__ q, const float* __restrict__ k, const float* __restrict__ v,
    const unsigned long long* __restrict__ maskbits, float* __restrict__ out)
{
    const int h = blockIdx.x >> 6, qb = blockIdx.x & 63;
    const int tid = threadIdx.x, wave = tid >> 6, lane = tid & 63;
    const int l16 = lane & 15, quad = lane >> 4;
    __shared__ __align__(16) unsigned short ks_hi[64][72];
    __shared__ __align__(16) unsigned short ks_lo[64][72];
    __shared__ __align__(16) unsigned short vt_hi[64][72];
    __shared__ __align__(16) unsigned short vt_lo[64][72];
    __shared__ __align__(16) unsigned short ps[4][16][72];

    const float4* qg = (const float4*)(q + ((size_t)h*L_ + (size_t)qb*64)*D_);
    for (int i4 = tid; i4 < 1024; i4 += 256) {
        float4 t = qg[i4];
        int r = i4 >> 4, c = (i4 & 15) << 2;
        ushort4 hi, lo;
        hi.x = f2bf(t.x); lo.x = f2bf(t.x - bf2f(hi.x));
        hi.y = f2bf(t.y); lo.y = f2bf(t.y - bf2f(hi.y));
        hi.z = f2bf(t.z); lo.z = f2bf(t.z - bf2f(hi.z));
        hi.w = f2bf(t.w); lo.w = f2bf(t.w - bf2f(hi.w));
        *(ushort4*)&ks_hi[r][c] = hi;
        *(ushort4*)&ks_lo[r][c] = lo;
    }
    const unsigned long long bm = maskbits[(h << 6) + qb];
    __syncthreads();
    bf16x8 qhi2[2], qlo2[2];
    #pragma unroll
    for (int kc = 0; kc < 2; ++kc) {
        qhi2[kc] = *(const bf16x8*)&ks_hi[wave*16 + l16][kc*32 + quad*8];
        qlo2[kc] = *(const bf16x8*)&ks_lo[wave*16 + l16][kc*32 + quad*8];
    }
    __syncthreads();
    float m_i[4], l_i[4];
    f32x4 oacc[4];
    #pragma unroll
    for (int r = 0; r < 4; ++r) { m_i[r] = -1e30f; l_i[r] = 0.f; }
    #pragma unroll
    for (int t = 0; t < 4; ++t) oacc[t] = (f32x4){0.f, 0.f, 0.f, 0.f};
    for (int kb = 0; kb < 64; ++kb) {
        if (!((bm >> kb) & 1ull)) continue;
        const float4* kg = (const float4*)(k + ((size_t)h*L_ + (size_t)kb*64)*D_);
        const float*  vg = v + ((size_t)h*L_ + (size_t)kb*64)*D_;
        for (int i4 = tid; i4 < 1024; i4 += 256) {
            float4 t = kg[i4];
            int r = i4 >> 4, c = (i4 & 15) << 2;
            ushort4 hi, lo;
            hi.x = f2bf(t.x); lo.x = f2bf(t.x - bf2f(hi.x));
            hi.y = f2bf(t.y); lo.y = f2bf(t.y - bf2f(hi.y));
            hi.z = f2bf(t.z); lo.z = f2bf(t.z - bf2f(hi.z));
            hi.w = f2bf(t.w); lo.w = f2bf(t.w - bf2f(hi.w));
            *(ushort4*)&ks_hi[r][c] = hi;
            *(ushort4*)&ks_lo[r][c] = lo;
        }
        for (int tsk = tid; tsk < 512; tsk += 256) {
            int rp = tsk >> 4;
            int c  = (tsk & 15) << 2;
            float4 a0 = *(const float4*)(vg + (size_t)(2*rp)*D_ + c);
            float4 a1 = *(const float4*)(vg + (size_t)(2*rp+1)*D_ + c);
            #pragma unroll
            for (int j = 0; j < 4; ++j) {
                float x0 = (j==0)?a0.x:(j==1)?a0.y:(j==2)?a0.z:a0.w;
                float x1 = (j==0)?a1.x:(j==1)?a1.y:(j==2)?a1.z:a1.w;
                unsigned short h0 = f2bf(x0), h1b = f2bf(x1);
                *(unsigned*)&vt_hi[c+j][2*rp] = (unsigned)h0 | ((unsigned)h1b << 16);
                unsigned short lo0 = f2bf(x0 - bf2f(h0)), lo1 = f2bf(x1 - bf2f(h1b));
                *(unsigned*)&vt_lo[c+j][2*rp] = (unsigned)lo0 | ((unsigned)lo1 << 16);
            }
        }
        __syncthreads();
        f32x4 sacc[4];
        #pragma unroll
        for (int t = 0; t < 4; ++t) sacc[t] = (f32x4){0.f, 0.f, 0.f, 0.f};
        #pragma unroll
        for (int t = 0; t < 4; ++t) {
            #pragma unroll
            for (int kc = 0; kc < 2; ++kc) {
                bf16x8 khi2 = *(const bf16x8*)&ks_hi[t*16 + l16][kc*32 + quad*8];
                bf16x8 klo2 = *(const bf16x8*)&ks_lo[t*16 + l16][kc*32 + quad*8];
                sacc[t] = __builtin_amdgcn_mfma_f32_16x16x32_bf16(qhi2[kc], khi2, sacc[t], 0, 0, 0);
                sacc[t] = __builtin_amdgcn_mfma_f32_16x16x32_bf16(qhi2[kc], klo2, sacc[t], 0, 0, 0);
                sacc[t] = __builtin_amdgcn_mfma_f32_16x16x32_bf16(qlo2[kc], khi2, sacc[t], 0, 0, 0);
            }
        }
        #pragma unroll
        for (int t = 0; t < 4; ++t) sacc[t] *= 0.125f;
        float rowmax[4];
        #pragma unroll
        for (int r = 0; r < 4; ++r)
            rowmax[r] = fmaxf(fmaxf(sacc[0][r], sacc[1][r]), fmaxf(sacc[2][r], sacc[3][r]));
        #pragma unroll
        for (int off = 1; off < 16; off <<= 1)
            #pragma unroll
            for (int r = 0; r < 4; ++r)
                rowmax[r] = fmaxf(rowmax[r], __shfl_xor(rowmax[r], off));
        float al[4], rs[4];
        #pragma unroll
        for (int r = 0; r < 4; ++r) {
            float mnew = fmaxf(m_i[r], rowmax[r]);
            al[r] = __expf(m_i[r] - mnew);
            m_i[r] = mnew;
            float acc = 0.f;
            #pragma unroll
            for (int t = 0; t < 4; ++t) {
                float p = __expf(sacc[t][r] - mnew);
                unsigned short pb = f2bf(p);
                ps[wave][quad*4 + r][t*16 + l16] = pb;
                acc += bf2f(pb);
            }
            rs[r] = acc;
        }
        #pragma unroll
        for (int off = 1; off < 16; off <<= 1)
            #pragma unroll
            for (int r = 0; r < 4; ++r)
                rs[r] += __shfl_xor(rs[r], off);
        #pragma unroll
        for (int r = 0; r < 4; ++r) l_i[r] = l_i[r] * al[r] + rs[r];
        #pragma unroll
        for (int t = 0; t < 4; ++t)
            #pragma unroll
            for (int r = 0; r < 4; ++r) oacc[t][r] *= al[r];
        bf16x8 pf[2];
        #pragma unroll
        for (int kc = 0; kc < 2; ++kc)
            pf[kc] = *(const bf16x8*)&ps[wave][l16][kc*32 + quad*8];
        #pragma unroll
        for (int t = 0; t < 4; ++t) {
            #pragma unroll
            for (int kc = 0; kc < 2; ++kc) {
                bf16x8 vhif = *(const bf16x8*)&vt_hi[t*16 + l16][kc*32 + quad*8];
                bf16x8 vlof = *(const bf16x8*)&vt_lo[t*16 + l16][kc*32 + quad*8];
                oacc[t] = __builtin_amdgcn_mfma_f32_16x16x32_bf16(pf[kc], vhif, oacc[t], 0, 0, 0);
                oacc[t] = __builtin_amdgcn_mfma_f32_16x16x32_bf16(pf[kc], vlof, oacc[t], 0, 0, 0);
            }
        }
        __syncthreads();
    }
    float* og = out + ((size_t)h*L_ + (size_t)qb*64)*D_ + (size_t)(wave*16 + quad*4)*D_;
    #pragma unroll
    for (int r = 0; r < 4; ++r) {
        float inv = 1.f / l_i[r];
        #pragma unroll
        for (int t = 0; t < 4; ++t)
            og[(size_t)r*D_ + t*16 + l16] = oacc[t][r] * inv;
    }
}

extern "C" void kernel_launch(void* const* d_in, const int* in_sizes, int n_in,
                              void* d_out, int out_size, void* d_ws, size_t ws_size,
                              hipStream_t stream) {
    const float* q = (const float*)d_in[0];
    const float* k = (const float*)d_in[1];
    const float* v = (const float*)d_in[2];
    const int* siq = (const int*)d_in[3];
    const int* sik = (const int*)d_in[4];
    float* out = (float*)d_out;

    char* ws = (char*)d_ws;
    unsigned long long* mask = (unsigned long long*)ws;          // 4 KB (fallback only)
    const size_t TEN = (size_t)H_*L_*D_;                         // 2,097,152 elems
    const size_t SKN = (size_t)H_*1024*64;                       //   524,288 elems
    unsigned short* qhi = (unsigned short*)(ws + 4096);
    unsigned short* qlo = qhi + TEN;
    unsigned short* khi = qlo + TEN;
    unsigned short* vth = khi + TEN;
    unsigned short* skh = vth + TEN;
    unsigned short* skl = skh + SKN;
    const size_t need = 4096 + (4*TEN + 2*SKN)*sizeof(unsigned short);  // ~18.9 MB

    if (ws_size >= need) {
        prep_kernel<<<dim3(H_*NB_), dim3(256), 0, stream>>>(q, k, v, sik, qhi, qlo, khi, vth, skh, skl);
        mask_attn<<<dim3(H_*NB_), dim3(256), 0, stream>>>(qhi, qlo, khi, vth, skh, skl, siq, out);
    } else {
        mask_kernel4<<<dim3(H_*NB_), dim3(256), 0, stream>>>(q, k, siq, sik, mask);
        attn_v3<<<dim3(H_*NB_), dim3(256), 0, stream>>>(q, k, v, mask, out);
    }
}